// Round 1
// baseline (804.331 us; speedup 1.0000x reference)
//
#include <hip/hip_runtime.h>

#define N_NODES 50000
#define E_EDGES 800000
#define E_TOT   (E_EDGES + N_NODES)
#define IN_C 512
#define HID 256
#define HEADS 8
#define HEAD_C 32
#define OUT_C 64

__device__ __forceinline__ float lrelu(float x) { return x > 0.f ? x : 0.2f * x; }

// ---------------- CSR build ----------------
__global__ void k_count(const int* __restrict__ ei, int* __restrict__ counts) {
  int e = blockIdx.x * blockDim.x + threadIdx.x;
  if (e >= E_TOT) return;
  int d = (e < E_EDGES) ? ei[E_EDGES + e] : (e - E_EDGES);
  atomicAdd(&counts[d], 1);
}

__global__ __launch_bounds__(1024) void k_scan(const int* __restrict__ counts,
                                               int* __restrict__ indptr,
                                               int* __restrict__ wptr) {
  __shared__ int wsum[16];
  __shared__ int s_run;
  int tid = threadIdx.x, lane = tid & 63, wid = tid >> 6;
  if (tid == 0) s_run = 0;
  __syncthreads();
  for (int base = 0; base < N_NODES; base += 1024) {
    int i = base + tid;
    int v = (i < N_NODES) ? counts[i] : 0;
    int run = s_run;
    int x = v;
    #pragma unroll
    for (int off = 1; off < 64; off <<= 1) {
      int t = __shfl_up(x, off);
      if (lane >= off) x += t;
    }
    if (lane == 63) wsum[wid] = x;
    __syncthreads();
    if (wid == 0 && lane < 16) {
      int wv = wsum[lane];
      #pragma unroll
      for (int off = 1; off < 16; off <<= 1) {
        int t = __shfl_up(wv, off);
        if (lane >= off) wv += t;
      }
      wsum[lane] = wv;
    }
    __syncthreads();
    int woff = wid ? wsum[wid - 1] : 0;
    int incl = x + woff;
    int excl = incl - v;
    if (i < N_NODES) { indptr[i] = run + excl; wptr[i] = run + excl; }
    __syncthreads();
    if (tid == 1023) s_run = run + incl;
    __syncthreads();
  }
  if (threadIdx.x == 0) indptr[N_NODES] = s_run;
}

__global__ void k_scatter(const int* __restrict__ ei, int* __restrict__ wptr,
                          int* __restrict__ csr_src) {
  int e = blockIdx.x * blockDim.x + threadIdx.x;
  if (e >= E_TOT) return;
  int s, d;
  if (e < E_EDGES) { s = ei[e]; d = ei[E_EDGES + e]; }
  else { s = d = e - E_EDGES; }
  int pos = atomicAdd(&wptr[d], 1);
  csr_src[pos] = s;
}

// ---------------- GEMM (fp32 vector, 128x{128,64} tile, 8x{8,4}/thread) ----------------
template <int BM, int BN, int BK>
__global__ __launch_bounds__(256) void k_gemm(const float* __restrict__ A,
                                              const float* __restrict__ B,
                                              float* __restrict__ C,
                                              int M, int N, int K) {
  __shared__ float sA[BK][BM + 4];
  __shared__ float sB[BK][BN + 4];
  const int TM = BM / 16, TN = BN / 16;
  int tid = threadIdx.x;
  int tx = tid & 15;
  int ty = tid >> 4;
  int row0 = blockIdx.x * BM;
  int col0 = blockIdx.y * BN;
  float acc[TM][TN] = {};
  for (int k0 = 0; k0 < K; k0 += BK) {
    for (int i = tid; i < BM * BK; i += 256) {
      int r = i / BK, c = i % BK;
      int gr = row0 + r;
      sA[c][r] = (gr < M) ? A[(size_t)gr * K + k0 + c] : 0.f;
    }
    for (int i = tid; i < BK * BN; i += 256) {
      int r = i / BN, c = i % BN;
      sB[r][c] = B[(size_t)(k0 + r) * N + col0 + c];
    }
    __syncthreads();
    #pragma unroll
    for (int kk = 0; kk < BK; ++kk) {
      float a[TM], b[TN];
      #pragma unroll
      for (int i = 0; i < TM; i++) a[i] = sA[kk][ty * TM + i];
      #pragma unroll
      for (int j = 0; j < TN; j++) b[j] = sB[kk][tx * TN + j];
      #pragma unroll
      for (int i = 0; i < TM; i++)
        #pragma unroll
        for (int j = 0; j < TN; j++)
          acc[i][j] += a[i] * b[j];
    }
    __syncthreads();
  }
  for (int i = 0; i < TM; i++) {
    int gr = row0 + ty * TM + i;
    if (gr >= M) continue;
    for (int j = 0; j < TN; j++)
      C[(size_t)gr * N + col0 + tx * TN + j] = acc[i][j];
  }
}

// ---------------- attention logits per node ----------------
__global__ void k_alpha1(const float* __restrict__ h1, const float* __restrict__ a_src,
                         const float* __restrict__ a_dst, float* __restrict__ as1,
                         float* __restrict__ ad1) {
  int t = blockIdx.x * blockDim.x + threadIdx.x;  // (n,h)
  if (t >= N_NODES * HEADS) return;
  int n = t >> 3, h = t & 7;
  const float* row = h1 + (size_t)n * HID + h * HEAD_C;
  const float* asr = a_src + h * HEAD_C;
  const float* adr = a_dst + h * HEAD_C;
  float ss = 0.f, sd = 0.f;
  #pragma unroll
  for (int c = 0; c < HEAD_C; c++) {
    float v = row[c];
    ss += v * asr[c];
    sd += v * adr[c];
  }
  as1[t] = ss;
  ad1[t] = sd;
}

__global__ void k_alpha2(const float* __restrict__ h2, const float* __restrict__ a_src,
                         const float* __restrict__ a_dst, float* __restrict__ as2,
                         float* __restrict__ ad2) {
  int wave = threadIdx.x >> 6, lane = threadIdx.x & 63;
  int n = blockIdx.x * 4 + wave;
  if (n >= N_NODES) return;
  float v = h2[(size_t)n * OUT_C + lane];
  float ss = v * a_src[lane];
  float sd = v * a_dst[lane];
  #pragma unroll
  for (int off = 32; off; off >>= 1) {
    ss += __shfl_xor(ss, off);
    sd += __shfl_xor(sd, off);
  }
  if (lane == 0) { as2[n] = ss; ad2[n] = sd; }
}

// ---------------- layer-1 aggregation: one wave per dst node ----------------
__global__ __launch_bounds__(256) void k_agg1(const float* __restrict__ h1,
                                              const int* __restrict__ indptr,
                                              const int* __restrict__ csr_src,
                                              const float* __restrict__ as1,
                                              const float* __restrict__ ad1,
                                              const float* __restrict__ b1,
                                              float* __restrict__ hp) {
  int wave = threadIdx.x >> 6, lane = threadIdx.x & 63;
  int node = blockIdx.x * 4 + wave;
  if (node >= N_NODES) return;
  int beg = indptr[node], end = indptr[node + 1];
  int h = lane >> 3;         // head for channels lane*4..lane*4+3
  int sub = lane & 7;
  float adst = ad1[node * 8 + h];

  // pass 1a: per-head max (8 lanes per head, stride 8 over edges)
  float m = -1e30f;
  for (int e = beg + sub; e < end; e += 8) {
    int s = csr_src[e];
    m = fmaxf(m, lrelu(as1[s * 8 + h] + adst));
  }
  m = fmaxf(m, __shfl_xor(m, 1));
  m = fmaxf(m, __shfl_xor(m, 2));
  m = fmaxf(m, __shfl_xor(m, 4));

  // pass 1b: denominator
  float dsum = 0.f;
  for (int e = beg + sub; e < end; e += 8) {
    int s = csr_src[e];
    dsum += __expf(lrelu(as1[s * 8 + h] + adst) - m);
  }
  dsum += __shfl_xor(dsum, 1);
  dsum += __shfl_xor(dsum, 2);
  dsum += __shfl_xor(dsum, 4);
  float inv = 1.f / (dsum + 1e-16f);

  // pass 2: weighted gather-accumulate (float4/lane = 1KB/edge coalesced)
  float4 acc = {0.f, 0.f, 0.f, 0.f};
  for (int e = beg; e < end; ++e) {
    int s = csr_src[e];
    float w = __expf(lrelu(as1[s * 8 + h] + adst) - m) * inv;
    float4 v = *reinterpret_cast<const float4*>(&h1[(size_t)s * HID + lane * 4]);
    acc.x += w * v.x; acc.y += w * v.y; acc.z += w * v.z; acc.w += w * v.w;
  }

  // epilogue: +b1, ELU
  const float4 bv = *reinterpret_cast<const float4*>(&b1[lane * 4]);
  float o[4] = {acc.x + bv.x, acc.y + bv.y, acc.z + bv.z, acc.w + bv.w};
  #pragma unroll
  for (int j = 0; j < 4; j++) o[j] = o[j] > 0.f ? o[j] : expm1f(o[j]);
  float4 ov = {o[0], o[1], o[2], o[3]};
  *reinterpret_cast<float4*>(&hp[(size_t)node * HID + lane * 4]) = ov;
}

// ---------------- layer-2 aggregation: one wave per dst node, lane = channel ----------------
__global__ __launch_bounds__(256) void k_agg2(const float* __restrict__ h2,
                                              const int* __restrict__ indptr,
                                              const int* __restrict__ csr_src,
                                              const float* __restrict__ as2,
                                              const float* __restrict__ ad2,
                                              const float* __restrict__ b2,
                                              float* __restrict__ out) {
  int wave = threadIdx.x >> 6, lane = threadIdx.x & 63;
  int node = blockIdx.x * 4 + wave;
  if (node >= N_NODES) return;
  int beg = indptr[node], end = indptr[node + 1];
  float adst = ad2[node];

  float m = -1e30f;
  for (int e = beg + lane; e < end; e += 64) {
    int s = csr_src[e];
    m = fmaxf(m, lrelu(as2[s] + adst));
  }
  #pragma unroll
  for (int off = 32; off; off >>= 1) m = fmaxf(m, __shfl_xor(m, off));

  float dsum = 0.f;
  for (int e = beg + lane; e < end; e += 64) {
    int s = csr_src[e];
    dsum += __expf(lrelu(as2[s] + adst) - m);
  }
  #pragma unroll
  for (int off = 32; off; off >>= 1) dsum += __shfl_xor(dsum, off);
  float inv = 1.f / (dsum + 1e-16f);

  float acc = 0.f;
  for (int e = beg; e < end; ++e) {
    int s = csr_src[e];
    float w = __expf(lrelu(as2[s] + adst) - m) * inv;
    acc += w * h2[(size_t)s * OUT_C + lane];
  }
  out[(size_t)node * OUT_C + lane] = acc + b2[lane];
}

extern "C" void kernel_launch(void* const* d_in, const int* in_sizes, int n_in,
                              void* d_out, int out_size, void* d_ws, size_t ws_size,
                              hipStream_t stream) {
  const float* x     = (const float*)d_in[0];
  const int*   ei    = (const int*)d_in[1];
  const float* W1    = (const float*)d_in[2];
  const float* asrc1 = (const float*)d_in[3];
  const float* adst1 = (const float*)d_in[4];
  const float* b1    = (const float*)d_in[5];
  const float* W2    = (const float*)d_in[6];
  const float* asrc2 = (const float*)d_in[7];
  const float* adst2 = (const float*)d_in[8];
  const float* b2    = (const float*)d_in[9];
  float* out = (float*)d_out;

  char* p = (char*)d_ws;
  size_t off = 0;
  auto take = [&](size_t bytes) -> void* {
    void* r = p + off;
    off += (bytes + 255) & ~(size_t)255;
    return r;
  };
  float* h1   = (float*)take((size_t)N_NODES * HID * 4);   // reused as h2 after agg1
  float* hp   = (float*)take((size_t)N_NODES * HID * 4);
  float* as1  = (float*)take((size_t)N_NODES * HEADS * 4);
  float* ad1  = (float*)take((size_t)N_NODES * HEADS * 4);
  float* as2  = (float*)take((size_t)N_NODES * 4);
  float* ad2  = (float*)take((size_t)N_NODES * 4);
  int* counts = (int*)take((size_t)N_NODES * 4);
  int* indptr = (int*)take((size_t)(N_NODES + 1) * 4);
  int* wptr   = (int*)take((size_t)(N_NODES + 1) * 4);
  int* csr    = (int*)take((size_t)E_TOT * 4);
  float* h2 = h1;

  // CSR build (shared by both layers)
  hipMemsetAsync(counts, 0, (size_t)N_NODES * 4, stream);
  k_count<<<(E_TOT + 255) / 256, 256, 0, stream>>>(ei, counts);
  k_scan<<<1, 1024, 0, stream>>>(counts, indptr, wptr);
  k_scatter<<<(E_TOT + 255) / 256, 256, 0, stream>>>(ei, wptr, csr);

  // layer 1
  dim3 g1((N_NODES + 127) / 128, HID / 128);
  k_gemm<128, 128, 8><<<g1, 256, 0, stream>>>(x, W1, h1, N_NODES, HID, IN_C);
  k_alpha1<<<(N_NODES * HEADS + 255) / 256, 256, 0, stream>>>(h1, asrc1, adst1, as1, ad1);
  k_agg1<<<(N_NODES + 3) / 4, 256, 0, stream>>>(h1, indptr, csr, as1, ad1, b1, hp);

  // layer 2
  dim3 g2((N_NODES + 127) / 128, 1);
  k_gemm<128, 64, 8><<<g2, 256, 0, stream>>>(hp, W2, h2, N_NODES, OUT_C, HID);
  k_alpha2<<<(N_NODES + 3) / 4, 256, 0, stream>>>(h2, asrc2, adst2, as2, ad2);
  k_agg2<<<(N_NODES + 3) / 4, 256, 0, stream>>>(h2, indptr, csr, as2, ad2, b2, out);
}

// Round 3
// 504.203 us; speedup vs baseline: 1.5953x; 1.5953x over previous
//
#include <hip/hip_runtime.h>

#define N_NODES 50000
#define M_PAD   50048            // 391 * 128
#define E_EDGES 800000
#define E_TOT   (E_EDGES + N_NODES)
#define IN_C 512
#define HID 256
#define HEADS 8
#define HEAD_C 32
#define OUT_C 64

typedef unsigned int uint;
typedef unsigned short ushort_t;
typedef __bf16 bf16x8 __attribute__((ext_vector_type(8)));
typedef float f32x4 __attribute__((ext_vector_type(4)));

__device__ __forceinline__ float lrelu(float x) { return x > 0.f ? x : 0.2f * x; }

__device__ __forceinline__ unsigned short f2bf(float f) {
  uint u = __float_as_uint(f);
  u += 0x7FFF + ((u >> 16) & 1);          // round-to-nearest-even
  return (unsigned short)(u >> 16);
}

// ---------------- CSR build ----------------
__global__ void k_count(const int* __restrict__ ei, int* __restrict__ counts) {
  int e = blockIdx.x * blockDim.x + threadIdx.x;
  if (e >= E_TOT) return;
  int d = (e < E_EDGES) ? ei[E_EDGES + e] : (e - E_EDGES);
  atomicAdd(&counts[d], 1);
}

__global__ __launch_bounds__(1024) void k_scan(const int* __restrict__ counts,
                                               int* __restrict__ indptr,
                                               int* __restrict__ wptr) {
  __shared__ int wsum[16];
  __shared__ int s_run;
  int tid = threadIdx.x, lane = tid & 63, wid = tid >> 6;
  if (tid == 0) s_run = 0;
  __syncthreads();
  for (int base = 0; base < N_NODES; base += 1024) {
    int i = base + tid;
    int v = (i < N_NODES) ? counts[i] : 0;
    int run = s_run;
    int x = v;
    #pragma unroll
    for (int off = 1; off < 64; off <<= 1) {
      int t = __shfl_up(x, off);
      if (lane >= off) x += t;
    }
    if (lane == 63) wsum[wid] = x;
    __syncthreads();
    if (wid == 0 && lane < 16) {
      int wv = wsum[lane];
      #pragma unroll
      for (int off = 1; off < 16; off <<= 1) {
        int t = __shfl_up(wv, off);
        if (lane >= off) wv += t;
      }
      wsum[lane] = wv;
    }
    __syncthreads();
    int woff = wid ? wsum[wid - 1] : 0;
    int incl = x + woff;
    int excl = incl - v;
    if (i < N_NODES) { indptr[i] = run + excl; wptr[i] = run + excl; }
    __syncthreads();
    if (tid == 1023) s_run = run + incl;
    __syncthreads();
  }
  if (threadIdx.x == 0) indptr[N_NODES] = s_run;
}

__global__ void k_scatter(const int* __restrict__ ei, int* __restrict__ wptr,
                          int* __restrict__ csr_src) {
  int e = blockIdx.x * blockDim.x + threadIdx.x;
  if (e >= E_TOT) return;
  int s, d;
  if (e < E_EDGES) { s = ei[e]; d = ei[E_EDGES + e]; }
  else { s = d = e - E_EDGES; }
  int pos = atomicAdd(&wptr[d], 1);
  csr_src[pos] = s;
}

// ---------------- fp32 -> bf16 tiled conversions ----------------
// tiled layout: [mtile][ktile][128][32] bf16, tile = 4096 elems (8 KB)

// x [50000][512] -> xb tiled (M_PAD rows, zero-padded)
__global__ void k_conv_x(const float* __restrict__ x, ushort_t* __restrict__ xb) {
  int t = blockIdx.x * blockDim.x + threadIdx.x;   // M_PAD * 64 threads
  int r = t >> 6, c8 = t & 63;                     // 8 bf16 per thread
  if (r >= M_PAD) return;
  unsigned short v[8];
  if (r < N_NODES) {
    const float* src = x + (size_t)r * IN_C + c8 * 8;
    #pragma unroll
    for (int i = 0; i < 8; i++) v[i] = f2bf(src[i]);
  } else {
    #pragma unroll
    for (int i = 0; i < 8; i++) v[i] = 0;
  }
  size_t addr = ((size_t)(r >> 7) * (IN_C / 32) + (c8 >> 2)) * 4096 + ((r & 127) << 5) + ((c8 & 3) << 3);
  uint4 pack;
  pack.x = v[0] | ((uint)v[1] << 16); pack.y = v[2] | ((uint)v[3] << 16);
  pack.z = v[4] | ((uint)v[5] << 16); pack.w = v[6] | ((uint)v[7] << 16);
  *reinterpret_cast<uint4*>(xb + addr) = pack;
}

// hp [50000][256] -> hpb tiled
__global__ void k_conv_h(const float* __restrict__ hp, ushort_t* __restrict__ hpb) {
  int t = blockIdx.x * blockDim.x + threadIdx.x;   // M_PAD * 32 threads
  int r = t >> 5, c8 = t & 31;
  if (r >= M_PAD) return;
  unsigned short v[8];
  if (r < N_NODES) {
    const float* src = hp + (size_t)r * HID + c8 * 8;
    #pragma unroll
    for (int i = 0; i < 8; i++) v[i] = f2bf(src[i]);
  } else {
    #pragma unroll
    for (int i = 0; i < 8; i++) v[i] = 0;
  }
  size_t addr = ((size_t)(r >> 7) * (HID / 32) + (c8 >> 2)) * 4096 + ((r & 127) << 5) + ((c8 & 3) << 3);
  uint4 pack;
  pack.x = v[0] | ((uint)v[1] << 16); pack.y = v[2] | ((uint)v[3] << 16);
  pack.z = v[4] | ((uint)v[5] << 16); pack.w = v[6] | ((uint)v[7] << 16);
  *reinterpret_cast<uint4*>(hpb + addr) = pack;
}

// W1 [512][256] -> transposed tiled [2][16][128][32] (n-major)
__global__ void k_conv_w1(const float* __restrict__ W1, ushort_t* __restrict__ w1t) {
  int t = blockIdx.x * blockDim.x + threadIdx.x;   // 512*256
  if (t >= IN_C * HID) return;
  int n = t & (HID - 1), k = t >> 8;
  size_t addr = ((size_t)(n >> 7) * (IN_C / 32) + (k >> 5)) * 4096 + ((n & 127) << 5) + (k & 31);
  w1t[addr] = f2bf(W1[(size_t)k * HID + n]);
}

// W2 [256][64] -> transposed tiled [8][64][32] (n-major, 64-row tiles)
__global__ void k_conv_w2(const float* __restrict__ W2, ushort_t* __restrict__ w2t) {
  int t = blockIdx.x * blockDim.x + threadIdx.x;   // 256*64
  if (t >= HID * OUT_C) return;
  int n = t & (OUT_C - 1), k = t >> 6;
  size_t addr = (size_t)(k >> 5) * (OUT_C * 32) + (n << 5) + (k & 31);
  w2t[addr] = f2bf(W2[(size_t)k * OUT_C + n]);
}

// ---------------- bf16 MFMA GEMM ----------------
// A tiled [mtile][KT][128][32], B tiled [ntile][KT][BN][32], C row-major [M][N]
template <int BN, int WAVES_M, int WAVES_N, int KT>
__global__ __launch_bounds__(256) void k_mm(const ushort_t* __restrict__ A,
                                            const ushort_t* __restrict__ B,
                                            float* __restrict__ C,
                                            int M, int N) {
  constexpr int WTM = 128 / WAVES_M;
  constexpr int WTN = BN / WAVES_N;
  constexpr int FM = WTM / 16;
  constexpr int FN = WTN / 16;
  __shared__ ushort_t sA[128][40];   // +16B pad: stride 80 B, conflict-free b128
  __shared__ ushort_t sB[BN][40];

  int tid = threadIdx.x;
  int wid = tid >> 6, lane = tid & 63;
  int wm = wid / WAVES_N, wn = wid % WAVES_N;
  int lr = lane & 15, kg = lane >> 4;

  f32x4 acc[FM][FN] = {};

  for (int kt = 0; kt < KT; ++kt) {
    // stage A: 128x32 bf16 = 8 KB, 32 B per thread
    {
      const ushort_t* pa = A + ((size_t)(blockIdx.x * KT + kt)) * 4096 + tid * 16;
      uint4 v0 = *reinterpret_cast<const uint4*>(pa);
      uint4 v1 = *reinterpret_cast<const uint4*>(pa + 8);
      int r = tid >> 1, k0 = (tid & 1) * 16;
      *reinterpret_cast<uint4*>(&sA[r][k0]) = v0;
      *reinterpret_cast<uint4*>(&sA[r][k0 + 8]) = v1;
    }
    // stage B: BN x 32 bf16
    if (tid < BN * 2) {
      const ushort_t* pb = B + ((size_t)(blockIdx.y * KT + kt)) * (BN * 32) + tid * 16;
      uint4 v0 = *reinterpret_cast<const uint4*>(pb);
      uint4 v1 = *reinterpret_cast<const uint4*>(pb + 8);
      int r = tid >> 1, k0 = (tid & 1) * 16;
      *reinterpret_cast<uint4*>(&sB[r][k0]) = v0;
      *reinterpret_cast<uint4*>(&sB[r][k0 + 8]) = v1;
    }
    __syncthreads();

    bf16x8 af[FM], bf[FN];
    #pragma unroll
    for (int i = 0; i < FM; i++)
      af[i] = *reinterpret_cast<const bf16x8*>(&sA[wm * WTM + i * 16 + lr][kg * 8]);
    #pragma unroll
    for (int j = 0; j < FN; j++)
      bf[j] = *reinterpret_cast<const bf16x8*>(&sB[wn * WTN + j * 16 + lr][kg * 8]);
    #pragma unroll
    for (int i = 0; i < FM; i++)
      #pragma unroll
      for (int j = 0; j < FN; j++)
        acc[i][j] = __builtin_amdgcn_mfma_f32_16x16x32_bf16(af[i], bf[j], acc[i][j], 0, 0, 0);
    __syncthreads();
  }

  // epilogue: D lane mapping col=lane&15, row=(lane>>4)*4+reg
  #pragma unroll
  for (int i = 0; i < FM; i++) {
    #pragma unroll
    for (int j = 0; j < FN; j++) {
      int gc = blockIdx.y * BN + wn * WTN + j * 16 + lr;
      #pragma unroll
      for (int q = 0; q < 4; q++) {
        int gr = blockIdx.x * 128 + wm * WTM + i * 16 + kg * 4 + q;
        if (gr < M) C[(size_t)gr * N + gc] = acc[i][j][q];
      }
    }
  }
}

// ---------------- attention logits per node ----------------
__global__ void k_alpha1(const float* __restrict__ h1, const float* __restrict__ a_src,
                         const float* __restrict__ a_dst, float* __restrict__ as1,
                         float* __restrict__ ad1) {
  int t = blockIdx.x * blockDim.x + threadIdx.x;  // (n,h)
  if (t >= N_NODES * HEADS) return;
  int n = t >> 3, h = t & 7;
  const float* row = h1 + (size_t)n * HID + h * HEAD_C;
  const float* asr = a_src + h * HEAD_C;
  const float* adr = a_dst + h * HEAD_C;
  float ss = 0.f, sd = 0.f;
  #pragma unroll
  for (int c = 0; c < HEAD_C; c += 4) {
    float4 v = *reinterpret_cast<const float4*>(row + c);
    float4 a = *reinterpret_cast<const float4*>(asr + c);
    float4 d = *reinterpret_cast<const float4*>(adr + c);
    ss += v.x * a.x + v.y * a.y + v.z * a.z + v.w * a.w;
    sd += v.x * d.x + v.y * d.y + v.z * d.z + v.w * d.w;
  }
  as1[t] = ss;
  ad1[t] = sd;
}

__global__ void k_alpha2(const float* __restrict__ h2, const float* __restrict__ a_src,
                         const float* __restrict__ a_dst, float* __restrict__ as2,
                         float* __restrict__ ad2) {
  int wave = threadIdx.x >> 6, lane = threadIdx.x & 63;
  int n = blockIdx.x * 4 + wave;
  if (n >= N_NODES) return;
  float v = h2[(size_t)n * OUT_C + lane];
  float ss = v * a_src[lane];
  float sd = v * a_dst[lane];
  #pragma unroll
  for (int off = 32; off; off >>= 1) {
    ss += __shfl_xor(ss, off);
    sd += __shfl_xor(sd, off);
  }
  if (lane == 0) { as2[n] = ss; ad2[n] = sd; }
}

// ---------------- layer-1 aggregation: one wave per dst node ----------------
__global__ __launch_bounds__(256) void k_agg1(const float* __restrict__ h1,
                                              const int* __restrict__ indptr,
                                              const int* __restrict__ csr_src,
                                              const float* __restrict__ as1,
                                              const float* __restrict__ ad1,
                                              const float* __restrict__ b1,
                                              float* __restrict__ hp) {
  int wave = threadIdx.x >> 6, lane = threadIdx.x & 63;
  int node = blockIdx.x * 4 + wave;
  if (node >= N_NODES) return;
  int beg = indptr[node], end = indptr[node + 1];
  int h = lane >> 3;
  int sub = lane & 7;
  float adst = ad1[node * 8 + h];

  float m = -1e30f;
  for (int e = beg + sub; e < end; e += 8) {
    int s = csr_src[e];
    m = fmaxf(m, lrelu(as1[s * 8 + h] + adst));
  }
  m = fmaxf(m, __shfl_xor(m, 1));
  m = fmaxf(m, __shfl_xor(m, 2));
  m = fmaxf(m, __shfl_xor(m, 4));

  float dsum = 0.f;
  for (int e = beg + sub; e < end; e += 8) {
    int s = csr_src[e];
    dsum += __expf(lrelu(as1[s * 8 + h] + adst) - m);
  }
  dsum += __shfl_xor(dsum, 1);
  dsum += __shfl_xor(dsum, 2);
  dsum += __shfl_xor(dsum, 4);
  float inv = 1.f / (dsum + 1e-16f);

  float4 acc = {0.f, 0.f, 0.f, 0.f};
  for (int e = beg; e < end; ++e) {
    int s = csr_src[e];
    float w = __expf(lrelu(as1[s * 8 + h] + adst) - m) * inv;
    float4 v = *reinterpret_cast<const float4*>(&h1[(size_t)s * HID + lane * 4]);
    acc.x += w * v.x; acc.y += w * v.y; acc.z += w * v.z; acc.w += w * v.w;
  }

  const float4 bv = *reinterpret_cast<const float4*>(&b1[lane * 4]);
  float o[4] = {acc.x + bv.x, acc.y + bv.y, acc.z + bv.z, acc.w + bv.w};
  #pragma unroll
  for (int j = 0; j < 4; j++) o[j] = o[j] > 0.f ? o[j] : expm1f(o[j]);
  float4 ov = {o[0], o[1], o[2], o[3]};
  *reinterpret_cast<float4*>(&hp[(size_t)node * HID + lane * 4]) = ov;
}

// ---------------- layer-2 aggregation ----------------
__global__ __launch_bounds__(256) void k_agg2(const float* __restrict__ h2,
                                              const int* __restrict__ indptr,
                                              const int* __restrict__ csr_src,
                                              const float* __restrict__ as2,
                                              const float* __restrict__ ad2,
                                              const float* __restrict__ b2,
                                              float* __restrict__ out) {
  int wave = threadIdx.x >> 6, lane = threadIdx.x & 63;
  int node = blockIdx.x * 4 + wave;
  if (node >= N_NODES) return;
  int beg = indptr[node], end = indptr[node + 1];
  float adst = ad2[node];

  float m = -1e30f;
  for (int e = beg + lane; e < end; e += 64) {
    int s = csr_src[e];
    m = fmaxf(m, lrelu(as2[s] + adst));
  }
  #pragma unroll
  for (int off = 32; off; off >>= 1) m = fmaxf(m, __shfl_xor(m, off));

  float dsum = 0.f;
  for (int e = beg + lane; e < end; e += 64) {
    int s = csr_src[e];
    dsum += __expf(lrelu(as2[s] + adst) - m);
  }
  #pragma unroll
  for (int off = 32; off; off >>= 1) dsum += __shfl_xor(dsum, off);
  float inv = 1.f / (dsum + 1e-16f);

  float acc = 0.f;
  for (int e = beg; e < end; ++e) {
    int s = csr_src[e];
    float w = __expf(lrelu(as2[s] + adst) - m) * inv;
    acc += w * h2[(size_t)s * OUT_C + lane];
  }
  out[(size_t)node * OUT_C + lane] = acc + b2[lane];
}

extern "C" void kernel_launch(void* const* d_in, const int* in_sizes, int n_in,
                              void* d_out, int out_size, void* d_ws, size_t ws_size,
                              hipStream_t stream) {
  const float* x     = (const float*)d_in[0];
  const int*   ei    = (const int*)d_in[1];
  const float* W1    = (const float*)d_in[2];
  const float* asrc1 = (const float*)d_in[3];
  const float* adst1 = (const float*)d_in[4];
  const float* b1    = (const float*)d_in[5];
  const float* W2    = (const float*)d_in[6];
  const float* asrc2 = (const float*)d_in[7];
  const float* adst2 = (const float*)d_in[8];
  const float* b2    = (const float*)d_in[9];
  float* out = (float*)d_out;

  char* p = (char*)d_ws;
  size_t off = 0;
  auto take = [&](size_t bytes) -> void* {
    void* r = p + off;
    off += (bytes + 255) & ~(size_t)255;
    return r;
  };
  // regionA: xb (bf16 tiled), later reused as hp (fp32)
  char* regionA = (char*)take((size_t)M_PAD * IN_C * 2);           // 51.25 MB
  // regionB: h1 (fp32), later hpb (bf16 tiled) + h2 (fp32)
  char* regionB = (char*)take((size_t)N_NODES * HID * 4);          // 51.2 MB
  float* as1  = (float*)take((size_t)N_NODES * HEADS * 4);
  float* ad1  = (float*)take((size_t)N_NODES * HEADS * 4);
  float* as2  = (float*)take((size_t)N_NODES * 4);
  float* ad2  = (float*)take((size_t)N_NODES * 4);
  int* counts = (int*)take((size_t)N_NODES * 4);
  int* indptr = (int*)take((size_t)(N_NODES + 1) * 4);
  int* wptr   = (int*)take((size_t)(N_NODES + 1) * 4);
  int* csr    = (int*)take((size_t)E_TOT * 4);
  ushort_t* w1t = (ushort_t*)take((size_t)IN_C * HID * 2);
  ushort_t* w2t = (ushort_t*)take((size_t)HID * OUT_C * 2);

  ushort_t* xb  = (ushort_t*)regionA;
  float*    hp  = (float*)regionA;                                  // after gemm1
  float*    h1  = (float*)regionB;
  ushort_t* hpb = (ushort_t*)regionB;                               // after agg1
  float*    h2  = (float*)(regionB + (size_t)M_PAD * HID * 2);      // 25.6 MB offset

  // CSR build (shared by both layers)
  hipMemsetAsync(counts, 0, (size_t)N_NODES * 4, stream);
  k_count<<<(E_TOT + 255) / 256, 256, 0, stream>>>(ei, counts);
  k_scan<<<1, 1024, 0, stream>>>(counts, indptr, wptr);
  k_scatter<<<(E_TOT + 255) / 256, 256, 0, stream>>>(ei, wptr, csr);

  // bf16 conversions (weights + x)
  k_conv_x<<<(M_PAD * 64 + 255) / 256, 256, 0, stream>>>(x, xb);
  k_conv_w1<<<(IN_C * HID + 255) / 256, 256, 0, stream>>>(W1, w1t);
  k_conv_w2<<<(HID * OUT_C + 255) / 256, 256, 0, stream>>>(W2, w2t);

  // layer 1
  dim3 g1(M_PAD / 128, HID / 128);
  k_mm<128, 2, 2, IN_C / 32><<<g1, 256, 0, stream>>>(xb, w1t, h1, N_NODES, HID);
  k_alpha1<<<(N_NODES * HEADS + 255) / 256, 256, 0, stream>>>(h1, asrc1, adst1, as1, ad1);
  k_agg1<<<(N_NODES + 3) / 4, 256, 0, stream>>>(h1, indptr, csr, as1, ad1, b1, hp);

  // layer 2
  k_conv_h<<<(M_PAD * 32 + 255) / 256, 256, 0, stream>>>(hp, hpb);
  dim3 g2(M_PAD / 128, 1);
  k_mm<64, 4, 1, HID / 32><<<g2, 256, 0, stream>>>(hpb, w2t, h2, N_NODES, OUT_C);
  k_alpha2<<<(N_NODES + 3) / 4, 256, 0, stream>>>(h2, asrc2, adst2, as2, ad2);
  k_agg2<<<(N_NODES + 3) / 4, 256, 0, stream>>>(h2, indptr, csr, as2, ad2, b2, out);
}

// Round 6
// 312.985 us; speedup vs baseline: 2.5699x; 1.6109x over previous
//
#include <hip/hip_runtime.h>

#define N_NODES 50000
#define M_PAD   50048            // 391 * 128
#define NBLK    196              // ceil(N_NODES/256)
#define E_EDGES 800000
#define E_TOT   (E_EDGES + N_NODES)
#define IN_C 512
#define HID 256
#define HEADS 8
#define OUT_C 64

typedef unsigned int uint;
typedef unsigned short ushort_t;
typedef __bf16 bf16x8 __attribute__((ext_vector_type(8)));
typedef float f32x4 __attribute__((ext_vector_type(4)));

__device__ __forceinline__ float lrelu(float x) { return x > 0.f ? x : 0.2f * x; }

__device__ __forceinline__ unsigned short f2bf(float f) {
  uint u = __float_as_uint(f);
  u += 0x7FFF + ((u >> 16) & 1);          // RNE
  return (unsigned short)(u >> 16);
}
__device__ __forceinline__ float bflo(uint u) { return __uint_as_float(u << 16); }
__device__ __forceinline__ float bfhi(uint u) { return __uint_as_float(u & 0xFFFF0000u); }

// ---------------- CSR build ----------------
__global__ void k_count(const int* __restrict__ ei, int* __restrict__ counts) {
  int e = blockIdx.x * blockDim.x + threadIdx.x;
  if (e >= E_TOT) return;
  int d = (e < E_EDGES) ? ei[E_EDGES + e] : (e - E_EDGES);
  atomicAdd(&counts[d], 1);
}

__global__ void k_bsum(const int* __restrict__ counts, int* __restrict__ bsum) {
  int i = blockIdx.x * 256 + threadIdx.x;
  int v = (i < N_NODES) ? counts[i] : 0;
  __shared__ int ws[4];
  int lane = threadIdx.x & 63, wid = threadIdx.x >> 6;
  #pragma unroll
  for (int off = 32; off; off >>= 1) v += __shfl_xor(v, off);
  if (lane == 0) ws[wid] = v;
  __syncthreads();
  if (threadIdx.x == 0) bsum[blockIdx.x] = ws[0] + ws[1] + ws[2] + ws[3];
}

__global__ void k_bscan(const int* __restrict__ bsum, int* __restrict__ boff) {
  int tid = threadIdx.x;
  int v = (tid < NBLK) ? bsum[tid] : 0;
  int lane = tid & 63, wid = tid >> 6;
  int x = v;
  #pragma unroll
  for (int off = 1; off < 64; off <<= 1) {
    int t = __shfl_up(x, off);
    if (lane >= off) x += t;
  }
  __shared__ int ws[4];
  if (lane == 63) ws[wid] = x;
  __syncthreads();
  int woff = 0;
  for (int w = 0; w < wid; w++) woff += ws[w];
  if (tid < NBLK) boff[tid] = x + woff - v;   // exclusive
}

__global__ void k_local(const int* __restrict__ counts, const int* __restrict__ boff,
                        int* __restrict__ indptr, int* __restrict__ wptr) {
  int b = blockIdx.x;
  int i = b * 256 + threadIdx.x;
  int v = (i < N_NODES) ? counts[i] : 0;
  int lane = threadIdx.x & 63, wid = threadIdx.x >> 6;
  int x = v;
  #pragma unroll
  for (int off = 1; off < 64; off <<= 1) {
    int t = __shfl_up(x, off);
    if (lane >= off) x += t;
  }
  __shared__ int ws[4];
  if (lane == 63) ws[wid] = x;
  __syncthreads();
  int woff = boff[b];
  for (int w = 0; w < wid; w++) woff += ws[w];
  int excl = woff + x - v;
  if (i < N_NODES) { indptr[i] = excl; wptr[i] = excl; }
  if (b == 0 && threadIdx.x == 0) indptr[N_NODES] = E_TOT;
}

__global__ void k_scatter(const int* __restrict__ ei, int* __restrict__ wptr,
                          int* __restrict__ csr_src) {
  int e = blockIdx.x * blockDim.x + threadIdx.x;
  if (e >= E_TOT) return;
  int s, d;
  if (e < E_EDGES) { s = ei[e]; d = ei[E_EDGES + e]; }
  else { s = d = e - E_EDGES; }
  int pos = atomicAdd(&wptr[d], 1);
  csr_src[pos] = s;
}

// ---------------- weight transposes (tiny) ----------------
// w1t[n][k] = bf16(W1[k][n]) : [256][512]
__global__ void k_conv_w1(const float* __restrict__ W1, ushort_t* __restrict__ w1t) {
  int t = blockIdx.x * blockDim.x + threadIdx.x;
  if (t >= HID * IN_C) return;
  int n = t >> 9, k = t & 511;
  w1t[t] = f2bf(W1[(size_t)k * HID + n]);
}
// w2t[n][k] = bf16(W2[k][n]) : [64][256]
__global__ void k_conv_w2(const float* __restrict__ W2, ushort_t* __restrict__ w2t) {
  int t = blockIdx.x * blockDim.x + threadIdx.x;
  if (t >= OUT_C * HID) return;
  int n = t >> 8, k = t & 255;
  w2t[t] = f2bf(W2[(size_t)k * OUT_C + n]);
}

// ---------------- GEMM1: h1b = bf16(x @ W1), fp32 A staged+converted in-kernel ----------------
// A: x [N][512] fp32 row-major. B: w1t [256][512] bf16 (n-major). C: h1b [N][256] bf16.
__global__ __launch_bounds__(512) void k_mm1(const float* __restrict__ A,
                                             const ushort_t* __restrict__ Bt,
                                             ushort_t* __restrict__ Cb) {
  __shared__ ushort_t sA[128][40];
  __shared__ ushort_t sB[256][40];
  int tid = threadIdx.x;
  int wid = tid >> 6, lane = tid & 63;
  int wm = wid >> 2, wn = wid & 3;        // 2 x 4 waves -> 64x64 per wave
  int lr = lane & 15, kg = lane >> 4;
  int row0 = blockIdx.x * 128;
  f32x4 acc[4][4] = {};

  for (int k0 = 0; k0 < IN_C; k0 += 32) {
    {  // stage A: 128x32 fp32 -> bf16 (4 threads/row, 8 floats each)
      int r = tid >> 2, cs = (tid & 3) * 8;
      int gr = row0 + r;
      unsigned short v[8];
      if (gr < N_NODES) {
        const float* src = A + (size_t)gr * IN_C + k0 + cs;
        float4 f0 = *reinterpret_cast<const float4*>(src);
        float4 f1 = *reinterpret_cast<const float4*>(src + 4);
        v[0] = f2bf(f0.x); v[1] = f2bf(f0.y); v[2] = f2bf(f0.z); v[3] = f2bf(f0.w);
        v[4] = f2bf(f1.x); v[5] = f2bf(f1.y); v[6] = f2bf(f1.z); v[7] = f2bf(f1.w);
      } else {
        #pragma unroll
        for (int i = 0; i < 8; i++) v[i] = 0;
      }
      uint4 pk;
      pk.x = v[0] | ((uint)v[1] << 16); pk.y = v[2] | ((uint)v[3] << 16);
      pk.z = v[4] | ((uint)v[5] << 16); pk.w = v[6] | ((uint)v[7] << 16);
      *reinterpret_cast<uint4*>(&sA[r][cs]) = pk;
    }
    {  // stage B: 256x32 bf16 (2 threads/row, 16 bf16 each)
      int n = tid >> 1, ks = (tid & 1) * 16;
      const ushort_t* src = Bt + (size_t)n * IN_C + k0 + ks;
      uint4 v0 = *reinterpret_cast<const uint4*>(src);
      uint4 v1 = *reinterpret_cast<const uint4*>(src + 8);
      *reinterpret_cast<uint4*>(&sB[n][ks]) = v0;
      *reinterpret_cast<uint4*>(&sB[n][ks + 8]) = v1;
    }
    __syncthreads();

    bf16x8 af[4], bfr[4];
    #pragma unroll
    for (int i = 0; i < 4; i++)
      af[i] = *reinterpret_cast<const bf16x8*>(&sA[wm * 64 + i * 16 + lr][kg * 8]);
    #pragma unroll
    for (int j = 0; j < 4; j++)
      bfr[j] = *reinterpret_cast<const bf16x8*>(&sB[wn * 64 + j * 16 + lr][kg * 8]);
    #pragma unroll
    for (int i = 0; i < 4; i++)
      #pragma unroll
      for (int j = 0; j < 4; j++)
        acc[i][j] = __builtin_amdgcn_mfma_f32_16x16x32_bf16(af[i], bfr[j], acc[i][j], 0, 0, 0);
    __syncthreads();
  }

  #pragma unroll
  for (int i = 0; i < 4; i++) {
    #pragma unroll
    for (int j = 0; j < 4; j++) {
      int gc = wn * 64 + j * 16 + lr;
      #pragma unroll
      for (int q = 0; q < 4; q++) {
        int gr = row0 + wm * 64 + i * 16 + kg * 4 + q;
        if (gr < N_NODES) Cb[(size_t)gr * HID + gc] = f2bf(acc[i][j][q]);
      }
    }
  }
}

// ---------------- GEMM2: h2 = fp32(hpb_tiled @ W2) ----------------
// A: hpb tiled [391][8][128][32] bf16. B: w2t [64][256] bf16. C: h2 [N][64] fp32.
__global__ __launch_bounds__(256) void k_mm2(const ushort_t* __restrict__ At,
                                             const ushort_t* __restrict__ Bt,
                                             float* __restrict__ C) {
  __shared__ ushort_t sA[128][40];
  __shared__ ushort_t sB[64][40];
  int tid = threadIdx.x;
  int wid = tid >> 6, lane = tid & 63;
  int lr = lane & 15, kg = lane >> 4;
  int row0 = blockIdx.x * 128;
  f32x4 acc[2][4] = {};

  for (int kt = 0; kt < HID / 32; ++kt) {
    {  // stage A from tiled: 4096 bf16 contiguous
      const ushort_t* src = At + ((size_t)blockIdx.x * 8 + kt) * 4096 + tid * 16;
      uint4 v0 = *reinterpret_cast<const uint4*>(src);
      uint4 v1 = *reinterpret_cast<const uint4*>(src + 8);
      int r = tid >> 1, ks = (tid & 1) * 16;
      *reinterpret_cast<uint4*>(&sA[r][ks]) = v0;
      *reinterpret_cast<uint4*>(&sA[r][ks + 8]) = v1;
    }
    if (tid < 128) {  // stage B: 64x32
      int n = tid >> 1, ks = (tid & 1) * 16;
      const ushort_t* src = Bt + (size_t)n * HID + kt * 32 + ks;
      uint4 v0 = *reinterpret_cast<const uint4*>(src);
      uint4 v1 = *reinterpret_cast<const uint4*>(src + 8);
      *reinterpret_cast<uint4*>(&sB[n][ks]) = v0;
      *reinterpret_cast<uint4*>(&sB[n][ks + 8]) = v1;
    }
    __syncthreads();

    bf16x8 af[2], bfr[4];
    #pragma unroll
    for (int i = 0; i < 2; i++)
      af[i] = *reinterpret_cast<const bf16x8*>(&sA[wid * 32 + i * 16 + lr][kg * 8]);
    #pragma unroll
    for (int j = 0; j < 4; j++)
      bfr[j] = *reinterpret_cast<const bf16x8*>(&sB[j * 16 + lr][kg * 8]);
    #pragma unroll
    for (int i = 0; i < 2; i++)
      #pragma unroll
      for (int j = 0; j < 4; j++)
        acc[i][j] = __builtin_amdgcn_mfma_f32_16x16x32_bf16(af[i], bfr[j], acc[i][j], 0, 0, 0);
    __syncthreads();
  }

  #pragma unroll
  for (int i = 0; i < 2; i++) {
    #pragma unroll
    for (int j = 0; j < 4; j++) {
      int gc = j * 16 + lr;
      #pragma unroll
      for (int q = 0; q < 4; q++) {
        int gr = row0 + wid * 32 + i * 16 + kg * 4 + q;
        if (gr < N_NODES) C[(size_t)gr * OUT_C + gc] = acc[i][j][q];
      }
    }
  }
}

// ---------------- attention logits ----------------
__global__ void k_alpha1(const ushort_t* __restrict__ h1b, const float* __restrict__ a_src,
                         const float* __restrict__ a_dst, float* __restrict__ as1,
                         float* __restrict__ ad1) {
  int t = blockIdx.x * blockDim.x + threadIdx.x;
  if (t >= N_NODES * HEADS) return;
  int n = t >> 3, h = t & 7;
  const ushort_t* row = h1b + (size_t)n * HID + h * 32;
  const float* asr = a_src + h * 32;
  const float* adr = a_dst + h * 32;
  float ss = 0.f, sd = 0.f;
  #pragma unroll
  for (int c = 0; c < 32; c += 8) {
    uint4 rv = *reinterpret_cast<const uint4*>(row + c);
    uint uu[4] = {rv.x, rv.y, rv.z, rv.w};
    #pragma unroll
    for (int q = 0; q < 4; q++) {
      float f0 = bflo(uu[q]), f1 = bfhi(uu[q]);
      ss += f0 * asr[c + q * 2] + f1 * asr[c + q * 2 + 1];
      sd += f0 * adr[c + q * 2] + f1 * adr[c + q * 2 + 1];
    }
  }
  as1[t] = ss;
  ad1[t] = sd;
}

__global__ void k_alpha2(const float* __restrict__ h2, const float* __restrict__ a_src,
                         const float* __restrict__ a_dst, float* __restrict__ as2,
                         float* __restrict__ ad2) {
  int wave = threadIdx.x >> 6, lane = threadIdx.x & 63;
  int n = blockIdx.x * 4 + wave;
  if (n >= N_NODES) return;
  float v = h2[(size_t)n * OUT_C + lane];
  float ss = v * a_src[lane];
  float sd = v * a_dst[lane];
  #pragma unroll
  for (int off = 32; off; off >>= 1) {
    ss += __shfl_xor(ss, off);
    sd += __shfl_xor(sd, off);
  }
  if (lane == 0) { as2[n] = ss; ad2[n] = sd; }
}

// ---------------- layer-1 aggregation: single pass, bf16 gather, 2 edges/iter ----------------
__global__ __launch_bounds__(256) void k_agg1(const ushort_t* __restrict__ h1b,
                                              const int* __restrict__ indptr,
                                              const int* __restrict__ csr_src,
                                              const float* __restrict__ as1,
                                              const float* __restrict__ ad1,
                                              const float* __restrict__ b1,
                                              ushort_t* __restrict__ hpb) {
  int wave = threadIdx.x >> 6, lane = threadIdx.x & 63;
  int node = blockIdx.x * 4 + wave;
  if (node >= N_NODES) return;
  int beg = indptr[node], end = indptr[node + 1];
  int half = lane >> 5, sl = lane & 31, h = sl >> 2;   // lane sl covers cols sl*8..sl*8+7
  float adst = ad1[node * 8 + h];

  float acc[8] = {};
  float dsum = 0.f;
  for (int e = beg + half; e < end; e += 2) {
    int s = csr_src[e];
    float w = __expf(lrelu(as1[s * 8 + h] + adst));
    uint4 rv = *reinterpret_cast<const uint4*>(&h1b[(size_t)s * HID + sl * 8]);
    acc[0] += w * bflo(rv.x); acc[1] += w * bfhi(rv.x);
    acc[2] += w * bflo(rv.y); acc[3] += w * bfhi(rv.y);
    acc[4] += w * bflo(rv.z); acc[5] += w * bfhi(rv.z);
    acc[6] += w * bflo(rv.w); acc[7] += w * bfhi(rv.w);
    dsum += w;
  }
  #pragma unroll
  for (int j = 0; j < 8; j++) acc[j] += __shfl_xor(acc[j], 32);
  dsum += __shfl_xor(dsum, 32);
  float inv = 1.f / (dsum + 1e-16f);

  if (half == 0) {
    unsigned short ob[8];
    #pragma unroll
    for (int j = 0; j < 8; j++) {
      float o = acc[j] * inv + b1[sl * 8 + j];
      o = o > 0.f ? o : expm1f(o);
      ob[j] = f2bf(o);
    }
    uint4 pk;
    pk.x = ob[0] | ((uint)ob[1] << 16); pk.y = ob[2] | ((uint)ob[3] << 16);
    pk.z = ob[4] | ((uint)ob[5] << 16); pk.w = ob[6] | ((uint)ob[7] << 16);
    size_t addr = ((size_t)(node >> 7) * 8 + (sl >> 2)) * 4096 + (size_t)(node & 127) * 32 + (sl & 3) * 8;
    *reinterpret_cast<uint4*>(&hpb[addr]) = pk;
  }
}

// ---------------- layer-2 aggregation: single pass, 2 edges/iter ----------------
__global__ __launch_bounds__(256) void k_agg2(const float* __restrict__ h2,
                                              const int* __restrict__ indptr,
                                              const int* __restrict__ csr_src,
                                              const float* __restrict__ as2,
                                              const float* __restrict__ ad2,
                                              const float* __restrict__ b2,
                                              float* __restrict__ out) {
  int wave = threadIdx.x >> 6, lane = threadIdx.x & 63;
  int node = blockIdx.x * 4 + wave;
  if (node >= N_NODES) return;
  int beg = indptr[node], end = indptr[node + 1];
  int half = lane >> 5, sl = lane & 31;   // lane sl covers cols 2sl, 2sl+1
  float adst = ad2[node];

  float ax = 0.f, ay = 0.f, dsum = 0.f;
  for (int e = beg + half; e < end; e += 2) {
    int s = csr_src[e];
    float w = __expf(lrelu(as2[s] + adst));
    float2 v = *reinterpret_cast<const float2*>(&h2[(size_t)s * OUT_C + sl * 2]);
    ax += w * v.x; ay += w * v.y; dsum += w;
  }
  ax += __shfl_xor(ax, 32);
  ay += __shfl_xor(ay, 32);
  dsum += __shfl_xor(dsum, 32);
  float inv = 1.f / (dsum + 1e-16f);
  if (half == 0) {
    float2 o = {ax * inv + b2[sl * 2], ay * inv + b2[sl * 2 + 1]};
    *reinterpret_cast<float2*>(&out[(size_t)node * OUT_C + sl * 2]) = o;
  }
}

extern "C" void kernel_launch(void* const* d_in, const int* in_sizes, int n_in,
                              void* d_out, int out_size, void* d_ws, size_t ws_size,
                              hipStream_t stream) {
  const float* x     = (const float*)d_in[0];
  const int*   ei    = (const int*)d_in[1];
  const float* W1    = (const float*)d_in[2];
  const float* asrc1 = (const float*)d_in[3];
  const float* adst1 = (const float*)d_in[4];
  const float* b1    = (const float*)d_in[5];
  const float* W2    = (const float*)d_in[6];
  const float* asrc2 = (const float*)d_in[7];
  const float* adst2 = (const float*)d_in[8];
  const float* b2    = (const float*)d_in[9];
  float* out = (float*)d_out;

  char* p = (char*)d_ws;
  size_t off = 0;
  auto take = [&](size_t bytes) -> void* {
    void* r = p + off;
    off += (bytes + 255) & ~(size_t)255;
    return r;
  };
  ushort_t* h1b  = (ushort_t*)take((size_t)N_NODES * HID * 2);        // 25.6 MB
  ushort_t* hpb  = (ushort_t*)take((size_t)(M_PAD / 128) * 8 * 4096 * 2); // 25.6 MB tiled
  float*    h2   = (float*)take((size_t)N_NODES * OUT_C * 4);         // 12.8 MB
  float*    as1  = (float*)take((size_t)N_NODES * HEADS * 4);
  float*    ad1  = (float*)take((size_t)N_NODES * HEADS * 4);
  float*    as2  = (float*)take((size_t)N_NODES * 4);
  float*    ad2  = (float*)take((size_t)N_NODES * 4);
  int* counts = (int*)take((size_t)N_NODES * 4);
  int* indptr = (int*)take((size_t)(N_NODES + 1) * 4);
  int* wptr   = (int*)take((size_t)(N_NODES + 1) * 4);
  int* bsum   = (int*)take((size_t)NBLK * 4);
  int* boff   = (int*)take((size_t)NBLK * 4);
  int* csr    = (int*)take((size_t)E_TOT * 4);
  ushort_t* w1t = (ushort_t*)take((size_t)IN_C * HID * 2);
  ushort_t* w2t = (ushort_t*)take((size_t)HID * OUT_C * 2);

  // CSR build (parallel scan)
  hipMemsetAsync(counts, 0, (size_t)N_NODES * 4, stream);
  k_count<<<(E_TOT + 255) / 256, 256, 0, stream>>>(ei, counts);
  k_bsum<<<NBLK, 256, 0, stream>>>(counts, bsum);
  k_bscan<<<1, 256, 0, stream>>>(bsum, boff);
  k_local<<<NBLK, 256, 0, stream>>>(counts, boff, indptr, wptr);
  k_scatter<<<(E_TOT + 255) / 256, 256, 0, stream>>>(ei, wptr, csr);

  // weight transposes
  k_conv_w1<<<(HID * IN_C + 255) / 256, 256, 0, stream>>>(W1, w1t);
  k_conv_w2<<<(OUT_C * HID + 255) / 256, 256, 0, stream>>>(W2, w2t);

  // layer 1
  k_mm1<<<M_PAD / 128, 512, 0, stream>>>(x, w1t, h1b);
  k_alpha1<<<(N_NODES * HEADS + 255) / 256, 256, 0, stream>>>(h1b, asrc1, adst1, as1, ad1);
  k_agg1<<<(N_NODES + 3) / 4, 256, 0, stream>>>(h1b, indptr, csr, as1, ad1, b1, hpb);

  // layer 2
  k_mm2<<<M_PAD / 128, 256, 0, stream>>>(hpb, w2t, h2);
  k_alpha2<<<(N_NODES + 3) / 4, 256, 0, stream>>>(h2, asrc2, adst2, as2, ad2);
  k_agg2<<<(N_NODES + 3) / 4, 256, 0, stream>>>(h2, indptr, csr, as2, ad2, b2, out);
}

// Round 7
// 292.737 us; speedup vs baseline: 2.7476x; 1.0692x over previous
//
#include <hip/hip_runtime.h>

#define N_NODES 50000
#define M_PAD   50048            // 391 * 128
#define NBLK    196              // ceil(N_NODES/256)
#define E_EDGES 800000
#define E_TOT   (E_EDGES + N_NODES)
#define IN_C 512
#define HID 256
#define HEADS 8
#define OUT_C 64

typedef unsigned int uint;
typedef unsigned short ushort_t;
typedef __bf16 bf16x8 __attribute__((ext_vector_type(8)));
typedef float f32x4 __attribute__((ext_vector_type(4)));

__device__ __forceinline__ float lrelu(float x) { return x > 0.f ? x : 0.2f * x; }

__device__ __forceinline__ unsigned short f2bf(float f) {
  uint u = __float_as_uint(f);
  u += 0x7FFF + ((u >> 16) & 1);          // RNE
  return (unsigned short)(u >> 16);
}
__device__ __forceinline__ float bflo(uint u) { return __uint_as_float(u << 16); }
__device__ __forceinline__ float bfhi(uint u) { return __uint_as_float(u & 0xFFFF0000u); }

// ---------------- CSR build ----------------
__global__ void k_count(const int* __restrict__ ei, int* __restrict__ counts) {
  int e = blockIdx.x * blockDim.x + threadIdx.x;
  if (e >= E_TOT) return;
  int d = (e < E_EDGES) ? ei[E_EDGES + e] : (e - E_EDGES);
  atomicAdd(&counts[d], 1);
}

__global__ void k_bsum(const int* __restrict__ counts, int* __restrict__ bsum) {
  int i = blockIdx.x * 256 + threadIdx.x;
  int v = (i < N_NODES) ? counts[i] : 0;
  __shared__ int ws[4];
  int lane = threadIdx.x & 63, wid = threadIdx.x >> 6;
  #pragma unroll
  for (int off = 32; off; off >>= 1) v += __shfl_xor(v, off);
  if (lane == 0) ws[wid] = v;
  __syncthreads();
  if (threadIdx.x == 0) bsum[blockIdx.x] = ws[0] + ws[1] + ws[2] + ws[3];
}

__global__ void k_bscan(const int* __restrict__ bsum, int* __restrict__ boff) {
  int tid = threadIdx.x;
  int v = (tid < NBLK) ? bsum[tid] : 0;
  int lane = tid & 63, wid = tid >> 6;
  int x = v;
  #pragma unroll
  for (int off = 1; off < 64; off <<= 1) {
    int t = __shfl_up(x, off);
    if (lane >= off) x += t;
  }
  __shared__ int ws[4];
  if (lane == 63) ws[wid] = x;
  __syncthreads();
  int woff = 0;
  for (int w = 0; w < wid; w++) woff += ws[w];
  if (tid < NBLK) boff[tid] = x + woff - v;   // exclusive
}

__global__ void k_local(const int* __restrict__ counts, const int* __restrict__ boff,
                        int* __restrict__ indptr, int* __restrict__ wptr) {
  int b = blockIdx.x;
  int i = b * 256 + threadIdx.x;
  int v = (i < N_NODES) ? counts[i] : 0;
  int lane = threadIdx.x & 63, wid = threadIdx.x >> 6;
  int x = v;
  #pragma unroll
  for (int off = 1; off < 64; off <<= 1) {
    int t = __shfl_up(x, off);
    if (lane >= off) x += t;
  }
  __shared__ int ws[4];
  if (lane == 63) ws[wid] = x;
  __syncthreads();
  int woff = boff[b];
  for (int w = 0; w < wid; w++) woff += ws[w];
  int excl = woff + x - v;
  if (i < N_NODES) { indptr[i] = excl; wptr[i] = excl; }
  if (b == 0 && threadIdx.x == 0) indptr[N_NODES] = E_TOT;
}

__global__ void k_scatter(const int* __restrict__ ei, int* __restrict__ wptr,
                          int* __restrict__ csr_src) {
  int e = blockIdx.x * blockDim.x + threadIdx.x;
  if (e >= E_TOT) return;
  int s, d;
  if (e < E_EDGES) { s = ei[e]; d = ei[E_EDGES + e]; }
  else { s = d = e - E_EDGES; }
  int pos = atomicAdd(&wptr[d], 1);
  csr_src[pos] = s;
}

// ---------------- weight transposes (tiny) ----------------
__global__ void k_conv_w1(const float* __restrict__ W1, ushort_t* __restrict__ w1t) {
  int t = blockIdx.x * blockDim.x + threadIdx.x;
  if (t >= HID * IN_C) return;
  int n = t >> 9, k = t & 511;
  w1t[t] = f2bf(W1[(size_t)k * HID + n]);
}
__global__ void k_conv_w2(const float* __restrict__ W2, ushort_t* __restrict__ w2t) {
  int t = blockIdx.x * blockDim.x + threadIdx.x;
  if (t >= OUT_C * HID) return;
  int n = t >> 8, k = t & 255;
  w2t[t] = f2bf(W2[(size_t)k * OUT_C + n]);
}

// ---------------- GEMM1: h1b = bf16(x @ W1) ----------------
__global__ __launch_bounds__(512) void k_mm1(const float* __restrict__ A,
                                             const ushort_t* __restrict__ Bt,
                                             ushort_t* __restrict__ Cb) {
  __shared__ ushort_t sA[128][40];
  __shared__ ushort_t sB[256][40];
  int tid = threadIdx.x;
  int wid = tid >> 6, lane = tid & 63;
  int wm = wid >> 2, wn = wid & 3;
  int lr = lane & 15, kg = lane >> 4;
  int row0 = blockIdx.x * 128;
  f32x4 acc[4][4] = {};

  for (int k0 = 0; k0 < IN_C; k0 += 32) {
    {
      int r = tid >> 2, cs = (tid & 3) * 8;
      int gr = row0 + r;
      unsigned short v[8];
      if (gr < N_NODES) {
        const float* src = A + (size_t)gr * IN_C + k0 + cs;
        float4 f0 = *reinterpret_cast<const float4*>(src);
        float4 f1 = *reinterpret_cast<const float4*>(src + 4);
        v[0] = f2bf(f0.x); v[1] = f2bf(f0.y); v[2] = f2bf(f0.z); v[3] = f2bf(f0.w);
        v[4] = f2bf(f1.x); v[5] = f2bf(f1.y); v[6] = f2bf(f1.z); v[7] = f2bf(f1.w);
      } else {
        #pragma unroll
        for (int i = 0; i < 8; i++) v[i] = 0;
      }
      uint4 pk;
      pk.x = v[0] | ((uint)v[1] << 16); pk.y = v[2] | ((uint)v[3] << 16);
      pk.z = v[4] | ((uint)v[5] << 16); pk.w = v[6] | ((uint)v[7] << 16);
      *reinterpret_cast<uint4*>(&sA[r][cs]) = pk;
    }
    {
      int n = tid >> 1, ks = (tid & 1) * 16;
      const ushort_t* src = Bt + (size_t)n * IN_C + k0 + ks;
      uint4 v0 = *reinterpret_cast<const uint4*>(src);
      uint4 v1 = *reinterpret_cast<const uint4*>(src + 8);
      *reinterpret_cast<uint4*>(&sB[n][ks]) = v0;
      *reinterpret_cast<uint4*>(&sB[n][ks + 8]) = v1;
    }
    __syncthreads();

    bf16x8 af[4], bfr[4];
    #pragma unroll
    for (int i = 0; i < 4; i++)
      af[i] = *reinterpret_cast<const bf16x8*>(&sA[wm * 64 + i * 16 + lr][kg * 8]);
    #pragma unroll
    for (int j = 0; j < 4; j++)
      bfr[j] = *reinterpret_cast<const bf16x8*>(&sB[wn * 64 + j * 16 + lr][kg * 8]);
    #pragma unroll
    for (int i = 0; i < 4; i++)
      #pragma unroll
      for (int j = 0; j < 4; j++)
        acc[i][j] = __builtin_amdgcn_mfma_f32_16x16x32_bf16(af[i], bfr[j], acc[i][j], 0, 0, 0);
    __syncthreads();
  }

  #pragma unroll
  for (int i = 0; i < 4; i++) {
    #pragma unroll
    for (int j = 0; j < 4; j++) {
      int gc = wn * 64 + j * 16 + lr;
      #pragma unroll
      for (int q = 0; q < 4; q++) {
        int gr = row0 + wm * 64 + i * 16 + kg * 4 + q;
        if (gr < N_NODES) Cb[(size_t)gr * HID + gc] = f2bf(acc[i][j][q]);
      }
    }
  }
}

// ---------------- GEMM2: h2 = fp32(hpb_tiled @ W2) ----------------
__global__ __launch_bounds__(256) void k_mm2(const ushort_t* __restrict__ At,
                                             const ushort_t* __restrict__ Bt,
                                             float* __restrict__ C) {
  __shared__ ushort_t sA[128][40];
  __shared__ ushort_t sB[64][40];
  int tid = threadIdx.x;
  int wid = tid >> 6, lane = tid & 63;
  int lr = lane & 15, kg = lane >> 4;
  int row0 = blockIdx.x * 128;
  f32x4 acc[2][4] = {};

  for (int kt = 0; kt < HID / 32; ++kt) {
    {
      const ushort_t* src = At + ((size_t)blockIdx.x * 8 + kt) * 4096 + tid * 16;
      uint4 v0 = *reinterpret_cast<const uint4*>(src);
      uint4 v1 = *reinterpret_cast<const uint4*>(src + 8);
      int r = tid >> 1, ks = (tid & 1) * 16;
      *reinterpret_cast<uint4*>(&sA[r][ks]) = v0;
      *reinterpret_cast<uint4*>(&sA[r][ks + 8]) = v1;
    }
    if (tid < 128) {
      int n = tid >> 1, ks = (tid & 1) * 16;
      const ushort_t* src = Bt + (size_t)n * HID + kt * 32 + ks;
      uint4 v0 = *reinterpret_cast<const uint4*>(src);
      uint4 v1 = *reinterpret_cast<const uint4*>(src + 8);
      *reinterpret_cast<uint4*>(&sB[n][ks]) = v0;
      *reinterpret_cast<uint4*>(&sB[n][ks + 8]) = v1;
    }
    __syncthreads();

    bf16x8 af[2], bfr[4];
    #pragma unroll
    for (int i = 0; i < 2; i++)
      af[i] = *reinterpret_cast<const bf16x8*>(&sA[wid * 32 + i * 16 + lr][kg * 8]);
    #pragma unroll
    for (int j = 0; j < 4; j++)
      bfr[j] = *reinterpret_cast<const bf16x8*>(&sB[j * 16 + lr][kg * 8]);
    #pragma unroll
    for (int i = 0; i < 2; i++)
      #pragma unroll
      for (int j = 0; j < 4; j++)
        acc[i][j] = __builtin_amdgcn_mfma_f32_16x16x32_bf16(af[i], bfr[j], acc[i][j], 0, 0, 0);
    __syncthreads();
  }

  #pragma unroll
  for (int i = 0; i < 2; i++) {
    #pragma unroll
    for (int j = 0; j < 4; j++) {
      int gc = j * 16 + lr;
      #pragma unroll
      for (int q = 0; q < 4; q++) {
        int gr = row0 + wid * 32 + i * 16 + kg * 4 + q;
        if (gr < N_NODES) C[(size_t)gr * OUT_C + gc] = acc[i][j][q];
      }
    }
  }
}

// ---------------- attention logits ----------------
__global__ void k_alpha1(const ushort_t* __restrict__ h1b, const float* __restrict__ a_src,
                         const float* __restrict__ a_dst, float* __restrict__ as1,
                         float* __restrict__ ad1) {
  int t = blockIdx.x * blockDim.x + threadIdx.x;
  if (t >= N_NODES * HEADS) return;
  int n = t >> 3, h = t & 7;
  const ushort_t* row = h1b + (size_t)n * HID + h * 32;
  const float* asr = a_src + h * 32;
  const float* adr = a_dst + h * 32;
  float ss = 0.f, sd = 0.f;
  #pragma unroll
  for (int c = 0; c < 32; c += 8) {
    uint4 rv = *reinterpret_cast<const uint4*>(row + c);
    uint uu[4] = {rv.x, rv.y, rv.z, rv.w};
    #pragma unroll
    for (int q = 0; q < 4; q++) {
      float f0 = bflo(uu[q]), f1 = bfhi(uu[q]);
      ss += f0 * asr[c + q * 2] + f1 * asr[c + q * 2 + 1];
      sd += f0 * adr[c + q * 2] + f1 * adr[c + q * 2 + 1];
    }
  }
  as1[t] = ss;
  ad1[t] = sd;
}

__global__ void k_alpha2(const float* __restrict__ h2, const float* __restrict__ a_src,
                         const float* __restrict__ a_dst, float* __restrict__ as2,
                         float* __restrict__ ad2) {
  int wave = threadIdx.x >> 6, lane = threadIdx.x & 63;
  int n = blockIdx.x * 4 + wave;
  if (n >= N_NODES) return;
  float v = h2[(size_t)n * OUT_C + lane];
  float ss = v * a_src[lane];
  float sd = v * a_dst[lane];
  #pragma unroll
  for (int off = 32; off; off >>= 1) {
    ss += __shfl_xor(ss, off);
    sd += __shfl_xor(sd, off);
  }
  if (lane == 0) { as2[n] = ss; ad2[n] = sd; }
}

// ---------------- layer-1 aggregation: unroll-2 per half (4 edges in flight/wave) ----------------
__global__ __launch_bounds__(256) void k_agg1(const ushort_t* __restrict__ h1b,
                                              const int* __restrict__ indptr,
                                              const int* __restrict__ csr_src,
                                              const float* __restrict__ as1,
                                              const float* __restrict__ ad1,
                                              const float* __restrict__ b1,
                                              ushort_t* __restrict__ hpb) {
  int wave = threadIdx.x >> 6, lane = threadIdx.x & 63;
  int node = blockIdx.x * 4 + wave;
  if (node >= N_NODES) return;
  int beg = indptr[node], end = indptr[node + 1];
  int half = lane >> 5, sl = lane & 31, h = sl >> 2;   // lane sl covers cols sl*8..sl*8+7
  float adst = ad1[node * 8 + h];

  float acc[8] = {};
  float dsum = 0.f;
  int e = beg + half;
  for (; e + 2 < end; e += 4) {       // edges e and e+2 (both in this half's stride)
    int s0 = csr_src[e];
    int s1 = csr_src[e + 2];
    float l0 = as1[s0 * 8 + h];
    float l1 = as1[s1 * 8 + h];
    uint4 r0 = *reinterpret_cast<const uint4*>(&h1b[(size_t)s0 * HID + sl * 8]);
    uint4 r1 = *reinterpret_cast<const uint4*>(&h1b[(size_t)s1 * HID + sl * 8]);
    float w0 = __expf(lrelu(l0 + adst));
    float w1 = __expf(lrelu(l1 + adst));
    acc[0] += w0 * bflo(r0.x); acc[1] += w0 * bfhi(r0.x);
    acc[2] += w0 * bflo(r0.y); acc[3] += w0 * bfhi(r0.y);
    acc[4] += w0 * bflo(r0.z); acc[5] += w0 * bfhi(r0.z);
    acc[6] += w0 * bflo(r0.w); acc[7] += w0 * bfhi(r0.w);
    dsum += w0;
    acc[0] += w1 * bflo(r1.x); acc[1] += w1 * bfhi(r1.x);
    acc[2] += w1 * bflo(r1.y); acc[3] += w1 * bfhi(r1.y);
    acc[4] += w1 * bflo(r1.z); acc[5] += w1 * bfhi(r1.z);
    acc[6] += w1 * bflo(r1.w); acc[7] += w1 * bfhi(r1.w);
    dsum += w1;
  }
  if (e < end) {
    int s = csr_src[e];
    float w = __expf(lrelu(as1[s * 8 + h] + adst));
    uint4 rv = *reinterpret_cast<const uint4*>(&h1b[(size_t)s * HID + sl * 8]);
    acc[0] += w * bflo(rv.x); acc[1] += w * bfhi(rv.x);
    acc[2] += w * bflo(rv.y); acc[3] += w * bfhi(rv.y);
    acc[4] += w * bflo(rv.z); acc[5] += w * bfhi(rv.z);
    acc[6] += w * bflo(rv.w); acc[7] += w * bfhi(rv.w);
    dsum += w;
  }
  #pragma unroll
  for (int j = 0; j < 8; j++) acc[j] += __shfl_xor(acc[j], 32);
  dsum += __shfl_xor(dsum, 32);
  float inv = 1.f / (dsum + 1e-16f);

  if (half == 0) {
    unsigned short ob[8];
    #pragma unroll
    for (int j = 0; j < 8; j++) {
      float o = acc[j] * inv + b1[sl * 8 + j];
      o = o > 0.f ? o : expm1f(o);
      ob[j] = f2bf(o);
    }
    uint4 pk;
    pk.x = ob[0] | ((uint)ob[1] << 16); pk.y = ob[2] | ((uint)ob[3] << 16);
    pk.z = ob[4] | ((uint)ob[5] << 16); pk.w = ob[6] | ((uint)ob[7] << 16);
    size_t addr = ((size_t)(node >> 7) * 8 + (sl >> 2)) * 4096 + (size_t)(node & 127) * 32 + (sl & 3) * 8;
    *reinterpret_cast<uint4*>(&hpb[addr]) = pk;
  }
}

// ---------------- layer-2 aggregation: unroll-2 per half ----------------
__global__ __launch_bounds__(256) void k_agg2(const float* __restrict__ h2,
                                              const int* __restrict__ indptr,
                                              const int* __restrict__ csr_src,
                                              const float* __restrict__ as2,
                                              const float* __restrict__ ad2,
                                              const float* __restrict__ b2,
                                              float* __restrict__ out) {
  int wave = threadIdx.x >> 6, lane = threadIdx.x & 63;
  int node = blockIdx.x * 4 + wave;
  if (node >= N_NODES) return;
  int beg = indptr[node], end = indptr[node + 1];
  int half = lane >> 5, sl = lane & 31;   // lane sl covers cols 2sl, 2sl+1
  float adst = ad2[node];

  float ax = 0.f, ay = 0.f, dsum = 0.f;
  int e = beg + half;
  for (; e + 2 < end; e += 4) {
    int s0 = csr_src[e];
    int s1 = csr_src[e + 2];
    float l0 = as2[s0];
    float l1 = as2[s1];
    float2 v0 = *reinterpret_cast<const float2*>(&h2[(size_t)s0 * OUT_C + sl * 2]);
    float2 v1 = *reinterpret_cast<const float2*>(&h2[(size_t)s1 * OUT_C + sl * 2]);
    float w0 = __expf(lrelu(l0 + adst));
    float w1 = __expf(lrelu(l1 + adst));
    ax += w0 * v0.x; ay += w0 * v0.y; dsum += w0;
    ax += w1 * v1.x; ay += w1 * v1.y; dsum += w1;
  }
  if (e < end) {
    int s = csr_src[e];
    float w = __expf(lrelu(as2[s] + adst));
    float2 v = *reinterpret_cast<const float2*>(&h2[(size_t)s * OUT_C + sl * 2]);
    ax += w * v.x; ay += w * v.y; dsum += w;
  }
  ax += __shfl_xor(ax, 32);
  ay += __shfl_xor(ay, 32);
  dsum += __shfl_xor(dsum, 32);
  float inv = 1.f / (dsum + 1e-16f);
  if (half == 0) {
    float2 o = {ax * inv + b2[sl * 2], ay * inv + b2[sl * 2 + 1]};
    *reinterpret_cast<float2*>(&out[(size_t)node * OUT_C + sl * 2]) = o;
  }
}

extern "C" void kernel_launch(void* const* d_in, const int* in_sizes, int n_in,
                              void* d_out, int out_size, void* d_ws, size_t ws_size,
                              hipStream_t stream) {
  const float* x     = (const float*)d_in[0];
  const int*   ei    = (const int*)d_in[1];
  const float* W1    = (const float*)d_in[2];
  const float* asrc1 = (const float*)d_in[3];
  const float* adst1 = (const float*)d_in[4];
  const float* b1    = (const float*)d_in[5];
  const float* W2    = (const float*)d_in[6];
  const float* asrc2 = (const float*)d_in[7];
  const float* adst2 = (const float*)d_in[8];
  const float* b2    = (const float*)d_in[9];
  float* out = (float*)d_out;

  char* p = (char*)d_ws;
  size_t off = 0;
  auto take = [&](size_t bytes) -> void* {
    void* r = p + off;
    off += (bytes + 255) & ~(size_t)255;
    return r;
  };
  ushort_t* h1b  = (ushort_t*)take((size_t)N_NODES * HID * 2);
  ushort_t* hpb  = (ushort_t*)take((size_t)(M_PAD / 128) * 8 * 4096 * 2);
  float*    h2   = (float*)take((size_t)N_NODES * OUT_C * 4);
  float*    as1  = (float*)take((size_t)N_NODES * HEADS * 4);
  float*    ad1  = (float*)take((size_t)N_NODES * HEADS * 4);
  float*    as2  = (float*)take((size_t)N_NODES * 4);
  float*    ad2  = (float*)take((size_t)N_NODES * 4);
  int* counts = (int*)take((size_t)N_NODES * 4);
  int* indptr = (int*)take((size_t)(N_NODES + 1) * 4);
  int* wptr   = (int*)take((size_t)(N_NODES + 1) * 4);
  int* bsum   = (int*)take((size_t)NBLK * 4);
  int* boff   = (int*)take((size_t)NBLK * 4);
  int* csr    = (int*)take((size_t)E_TOT * 4);
  ushort_t* w1t = (ushort_t*)take((size_t)IN_C * HID * 2);
  ushort_t* w2t = (ushort_t*)take((size_t)HID * OUT_C * 2);

  // CSR build (parallel scan)
  hipMemsetAsync(counts, 0, (size_t)N_NODES * 4, stream);
  k_count<<<(E_TOT + 255) / 256, 256, 0, stream>>>(ei, counts);
  k_bsum<<<NBLK, 256, 0, stream>>>(counts, bsum);
  k_bscan<<<1, 256, 0, stream>>>(bsum, boff);
  k_local<<<NBLK, 256, 0, stream>>>(counts, boff, indptr, wptr);
  k_scatter<<<(E_TOT + 255) / 256, 256, 0, stream>>>(ei, wptr, csr);

  // weight transposes
  k_conv_w1<<<(HID * IN_C + 255) / 256, 256, 0, stream>>>(W1, w1t);
  k_conv_w2<<<(OUT_C * HID + 255) / 256, 256, 0, stream>>>(W2, w2t);

  // layer 1
  k_mm1<<<M_PAD / 128, 512, 0, stream>>>(x, w1t, h1b);
  k_alpha1<<<(N_NODES * HEADS + 255) / 256, 256, 0, stream>>>(h1b, asrc1, adst1, as1, ad1);
  k_agg1<<<(N_NODES + 3) / 4, 256, 0, stream>>>(h1b, indptr, csr, as1, ad1, b1, hpb);

  // layer 2
  k_mm2<<<M_PAD / 128, 256, 0, stream>>>(hpb, w2t, h2);
  k_alpha2<<<(N_NODES + 3) / 4, 256, 0, stream>>>(h2, asrc2, adst2, as2, ad2);
  k_agg2<<<(N_NODES + 3) / 4, 256, 0, stream>>>(h2, indptr, csr, as2, ad2, b2, out);
}

// Round 8
// 286.331 us; speedup vs baseline: 2.8091x; 1.0224x over previous
//
#include <hip/hip_runtime.h>

#define N_NODES 50000
#define M_PAD   50048            // 391 * 128
#define NBLK    196              // ceil(N_NODES/256)
#define E_EDGES 800000
#define E_TOT   (E_EDGES + N_NODES)
#define IN_C 512
#define HID 256
#define HEADS 8
#define OUT_C 64

typedef unsigned int uint;
typedef unsigned short ushort_t;
typedef __bf16 bf16x8 __attribute__((ext_vector_type(8)));
typedef float f32x4 __attribute__((ext_vector_type(4)));
typedef float f32x2 __attribute__((ext_vector_type(2)));

__device__ __forceinline__ float lrelu(float x) { return x > 0.f ? x : 0.2f * x; }

__device__ __forceinline__ unsigned short f2bf(float f) {
  uint u = __float_as_uint(f);
  u += 0x7FFF + ((u >> 16) & 1);          // RNE
  return (unsigned short)(u >> 16);
}
__device__ __forceinline__ float bflo(uint u) { return __uint_as_float(u << 16); }
__device__ __forceinline__ float bfhi(uint u) { return __uint_as_float(u & 0xFFFF0000u); }
__device__ __forceinline__ f32x2 unp2(uint u) {
  f32x2 r; r.x = bflo(u); r.y = bfhi(u); return r;
}

// ---------------- CSR build ----------------
__global__ void k_count(const int* __restrict__ ei, int* __restrict__ counts) {
  int e = blockIdx.x * blockDim.x + threadIdx.x;
  if (e >= E_TOT) return;
  int d = (e < E_EDGES) ? ei[E_EDGES + e] : (e - E_EDGES);
  atomicAdd(&counts[d], 1);
}

__global__ void k_bsum(const int* __restrict__ counts, int* __restrict__ bsum) {
  int i = blockIdx.x * 256 + threadIdx.x;
  int v = (i < N_NODES) ? counts[i] : 0;
  __shared__ int ws[4];
  int lane = threadIdx.x & 63, wid = threadIdx.x >> 6;
  #pragma unroll
  for (int off = 32; off; off >>= 1) v += __shfl_xor(v, off);
  if (lane == 0) ws[wid] = v;
  __syncthreads();
  if (threadIdx.x == 0) bsum[blockIdx.x] = ws[0] + ws[1] + ws[2] + ws[3];
}

__global__ void k_bscan(const int* __restrict__ bsum, int* __restrict__ boff) {
  int tid = threadIdx.x;
  int v = (tid < NBLK) ? bsum[tid] : 0;
  int lane = tid & 63, wid = tid >> 6;
  int x = v;
  #pragma unroll
  for (int off = 1; off < 64; off <<= 1) {
    int t = __shfl_up(x, off);
    if (lane >= off) x += t;
  }
  __shared__ int ws[4];
  if (lane == 63) ws[wid] = x;
  __syncthreads();
  int woff = 0;
  for (int w = 0; w < wid; w++) woff += ws[w];
  if (tid < NBLK) boff[tid] = x + woff - v;   // exclusive
}

__global__ void k_local(const int* __restrict__ counts, const int* __restrict__ boff,
                        int* __restrict__ indptr, int* __restrict__ wptr) {
  int b = blockIdx.x;
  int i = b * 256 + threadIdx.x;
  int v = (i < N_NODES) ? counts[i] : 0;
  int lane = threadIdx.x & 63, wid = threadIdx.x >> 6;
  int x = v;
  #pragma unroll
  for (int off = 1; off < 64; off <<= 1) {
    int t = __shfl_up(x, off);
    if (lane >= off) x += t;
  }
  __shared__ int ws[4];
  if (lane == 63) ws[wid] = x;
  __syncthreads();
  int woff = boff[b];
  for (int w = 0; w < wid; w++) woff += ws[w];
  int excl = woff + x - v;
  if (i < N_NODES) { indptr[i] = excl; wptr[i] = excl; }
  if (b == 0 && threadIdx.x == 0) indptr[N_NODES] = E_TOT;
}

__global__ void k_scatter(const int* __restrict__ ei, int* __restrict__ wptr,
                          int* __restrict__ csr_src) {
  int e = blockIdx.x * blockDim.x + threadIdx.x;
  if (e >= E_TOT) return;
  int s, d;
  if (e < E_EDGES) { s = ei[e]; d = ei[E_EDGES + e]; }
  else { s = d = e - E_EDGES; }
  int pos = atomicAdd(&wptr[d], 1);
  csr_src[pos] = s;
}

// ---------------- weight transposes (tiny) ----------------
__global__ void k_conv_w1(const float* __restrict__ W1, ushort_t* __restrict__ w1t) {
  int t = blockIdx.x * blockDim.x + threadIdx.x;
  if (t >= HID * IN_C) return;
  int n = t >> 9, k = t & 511;
  w1t[t] = f2bf(W1[(size_t)k * HID + n]);
}
__global__ void k_conv_w2(const float* __restrict__ W2, ushort_t* __restrict__ w2t) {
  int t = blockIdx.x * blockDim.x + threadIdx.x;
  if (t >= OUT_C * HID) return;
  int n = t >> 8, k = t & 255;
  w2t[t] = f2bf(W2[(size_t)k * OUT_C + n]);
}

// ---------------- GEMM1: h1b = bf16(x @ W1) ----------------
__global__ __launch_bounds__(512) void k_mm1(const float* __restrict__ A,
                                             const ushort_t* __restrict__ Bt,
                                             ushort_t* __restrict__ Cb) {
  __shared__ ushort_t sA[128][40];
  __shared__ ushort_t sB[256][40];
  int tid = threadIdx.x;
  int wid = tid >> 6, lane = tid & 63;
  int wm = wid >> 2, wn = wid & 3;
  int lr = lane & 15, kg = lane >> 4;
  int row0 = blockIdx.x * 128;
  f32x4 acc[4][4] = {};

  for (int k0 = 0; k0 < IN_C; k0 += 32) {
    {
      int r = tid >> 2, cs = (tid & 3) * 8;
      int gr = row0 + r;
      unsigned short v[8];
      if (gr < N_NODES) {
        const float* src = A + (size_t)gr * IN_C + k0 + cs;
        float4 f0 = *reinterpret_cast<const float4*>(src);
        float4 f1 = *reinterpret_cast<const float4*>(src + 4);
        v[0] = f2bf(f0.x); v[1] = f2bf(f0.y); v[2] = f2bf(f0.z); v[3] = f2bf(f0.w);
        v[4] = f2bf(f1.x); v[5] = f2bf(f1.y); v[6] = f2bf(f1.z); v[7] = f2bf(f1.w);
      } else {
        #pragma unroll
        for (int i = 0; i < 8; i++) v[i] = 0;
      }
      uint4 pk;
      pk.x = v[0] | ((uint)v[1] << 16); pk.y = v[2] | ((uint)v[3] << 16);
      pk.z = v[4] | ((uint)v[5] << 16); pk.w = v[6] | ((uint)v[7] << 16);
      *reinterpret_cast<uint4*>(&sA[r][cs]) = pk;
    }
    {
      int n = tid >> 1, ks = (tid & 1) * 16;
      const ushort_t* src = Bt + (size_t)n * IN_C + k0 + ks;
      uint4 v0 = *reinterpret_cast<const uint4*>(src);
      uint4 v1 = *reinterpret_cast<const uint4*>(src + 8);
      *reinterpret_cast<uint4*>(&sB[n][ks]) = v0;
      *reinterpret_cast<uint4*>(&sB[n][ks + 8]) = v1;
    }
    __syncthreads();

    bf16x8 af[4], bfr[4];
    #pragma unroll
    for (int i = 0; i < 4; i++)
      af[i] = *reinterpret_cast<const bf16x8*>(&sA[wm * 64 + i * 16 + lr][kg * 8]);
    #pragma unroll
    for (int j = 0; j < 4; j++)
      bfr[j] = *reinterpret_cast<const bf16x8*>(&sB[wn * 64 + j * 16 + lr][kg * 8]);
    #pragma unroll
    for (int i = 0; i < 4; i++)
      #pragma unroll
      for (int j = 0; j < 4; j++)
        acc[i][j] = __builtin_amdgcn_mfma_f32_16x16x32_bf16(af[i], bfr[j], acc[i][j], 0, 0, 0);
    __syncthreads();
  }

  #pragma unroll
  for (int i = 0; i < 4; i++) {
    #pragma unroll
    for (int j = 0; j < 4; j++) {
      int gc = wn * 64 + j * 16 + lr;
      #pragma unroll
      for (int q = 0; q < 4; q++) {
        int gr = row0 + wm * 64 + i * 16 + kg * 4 + q;
        if (gr < N_NODES) Cb[(size_t)gr * HID + gc] = f2bf(acc[i][j][q]);
      }
    }
  }
}

// ---------------- GEMM2: h2 = fp32(hpb_tiled @ W2) ----------------
__global__ __launch_bounds__(256) void k_mm2(const ushort_t* __restrict__ At,
                                             const ushort_t* __restrict__ Bt,
                                             float* __restrict__ C) {
  __shared__ ushort_t sA[128][40];
  __shared__ ushort_t sB[64][40];
  int tid = threadIdx.x;
  int wid = tid >> 6, lane = tid & 63;
  int lr = lane & 15, kg = lane >> 4;
  int row0 = blockIdx.x * 128;
  f32x4 acc[2][4] = {};

  for (int kt = 0; kt < HID / 32; ++kt) {
    {
      const ushort_t* src = At + ((size_t)blockIdx.x * 8 + kt) * 4096 + tid * 16;
      uint4 v0 = *reinterpret_cast<const uint4*>(src);
      uint4 v1 = *reinterpret_cast<const uint4*>(src + 8);
      int r = tid >> 1, ks = (tid & 1) * 16;
      *reinterpret_cast<uint4*>(&sA[r][ks]) = v0;
      *reinterpret_cast<uint4*>(&sA[r][ks + 8]) = v1;
    }
    if (tid < 128) {
      int n = tid >> 1, ks = (tid & 1) * 16;
      const ushort_t* src = Bt + (size_t)n * HID + kt * 32 + ks;
      uint4 v0 = *reinterpret_cast<const uint4*>(src);
      uint4 v1 = *reinterpret_cast<const uint4*>(src + 8);
      *reinterpret_cast<uint4*>(&sB[n][ks]) = v0;
      *reinterpret_cast<uint4*>(&sB[n][ks + 8]) = v1;
    }
    __syncthreads();

    bf16x8 af[2], bfr[4];
    #pragma unroll
    for (int i = 0; i < 2; i++)
      af[i] = *reinterpret_cast<const bf16x8*>(&sA[wid * 32 + i * 16 + lr][kg * 8]);
    #pragma unroll
    for (int j = 0; j < 4; j++)
      bfr[j] = *reinterpret_cast<const bf16x8*>(&sB[j * 16 + lr][kg * 8]);
    #pragma unroll
    for (int i = 0; i < 2; i++)
      #pragma unroll
      for (int j = 0; j < 4; j++)
        acc[i][j] = __builtin_amdgcn_mfma_f32_16x16x32_bf16(af[i], bfr[j], acc[i][j], 0, 0, 0);
    __syncthreads();
  }

  #pragma unroll
  for (int i = 0; i < 2; i++) {
    #pragma unroll
    for (int j = 0; j < 4; j++) {
      int gc = j * 16 + lr;
      #pragma unroll
      for (int q = 0; q < 4; q++) {
        int gr = row0 + wid * 32 + i * 16 + kg * 4 + q;
        if (gr < N_NODES) C[(size_t)gr * OUT_C + gc] = acc[i][j][q];
      }
    }
  }
}

// ---------------- attention logits ----------------
__global__ void k_alpha1(const ushort_t* __restrict__ h1b, const float* __restrict__ a_src,
                         const float* __restrict__ a_dst, float* __restrict__ as1,
                         float* __restrict__ ad1) {
  int t = blockIdx.x * blockDim.x + threadIdx.x;
  if (t >= N_NODES * HEADS) return;
  int n = t >> 3, h = t & 7;
  const ushort_t* row = h1b + (size_t)n * HID + h * 32;
  const float* asr = a_src + h * 32;
  const float* adr = a_dst + h * 32;
  float ss = 0.f, sd = 0.f;
  #pragma unroll
  for (int c = 0; c < 32; c += 8) {
    uint4 rv = *reinterpret_cast<const uint4*>(row + c);
    uint uu[4] = {rv.x, rv.y, rv.z, rv.w};
    #pragma unroll
    for (int q = 0; q < 4; q++) {
      float f0 = bflo(uu[q]), f1 = bfhi(uu[q]);
      ss += f0 * asr[c + q * 2] + f1 * asr[c + q * 2 + 1];
      sd += f0 * adr[c + q * 2] + f1 * adr[c + q * 2 + 1];
    }
  }
  as1[t] = ss;
  ad1[t] = sd;
}

__global__ void k_alpha2(const float* __restrict__ h2, const float* __restrict__ a_src,
                         const float* __restrict__ a_dst, float* __restrict__ as2,
                         float* __restrict__ ad2) {
  int wave = threadIdx.x >> 6, lane = threadIdx.x & 63;
  int n = blockIdx.x * 4 + wave;
  if (n >= N_NODES) return;
  float v = h2[(size_t)n * OUT_C + lane];
  float ss = v * a_src[lane];
  float sd = v * a_dst[lane];
  #pragma unroll
  for (int off = 32; off; off >>= 1) {
    ss += __shfl_xor(ss, off);
    sd += __shfl_xor(sd, off);
  }
  if (lane == 0) { as2[n] = ss; ad2[n] = sd; }
}

// ---------------- layer-1 aggregation: unroll-4 per half (8 edges in flight/wave) ----------------
__global__ __launch_bounds__(256) void k_agg1(const ushort_t* __restrict__ h1b,
                                              const int* __restrict__ indptr,
                                              const int* __restrict__ csr_src,
                                              const float* __restrict__ as1,
                                              const float* __restrict__ ad1,
                                              const float* __restrict__ b1,
                                              ushort_t* __restrict__ hpb) {
  int wave = threadIdx.x >> 6, lane = threadIdx.x & 63;
  int node = blockIdx.x * 4 + wave;
  if (node >= N_NODES) return;
  int beg = indptr[node], end = indptr[node + 1];
  int half = lane >> 5, sl = lane & 31, h = sl >> 2;   // lane sl covers cols sl*8..sl*8+7
  float adst = ad1[node * 8 + h];

  f32x2 a0 = {0.f, 0.f}, a1 = {0.f, 0.f}, a2 = {0.f, 0.f}, a3 = {0.f, 0.f};
  float dsum = 0.f;
  int e = beg + half;
  for (; e + 6 < end; e += 8) {        // 4 edges per iter in this half's stride
    int s0 = csr_src[e];
    int s1 = csr_src[e + 2];
    int s2 = csr_src[e + 4];
    int s3 = csr_src[e + 6];
    float l0 = as1[s0 * 8 + h];
    float l1 = as1[s1 * 8 + h];
    float l2 = as1[s2 * 8 + h];
    float l3 = as1[s3 * 8 + h];
    uint4 r0 = *reinterpret_cast<const uint4*>(&h1b[(size_t)s0 * HID + sl * 8]);
    uint4 r1 = *reinterpret_cast<const uint4*>(&h1b[(size_t)s1 * HID + sl * 8]);
    uint4 r2 = *reinterpret_cast<const uint4*>(&h1b[(size_t)s2 * HID + sl * 8]);
    uint4 r3 = *reinterpret_cast<const uint4*>(&h1b[(size_t)s3 * HID + sl * 8]);
    float w0 = __expf(lrelu(l0 + adst));
    float w1 = __expf(lrelu(l1 + adst));
    float w2 = __expf(lrelu(l2 + adst));
    float w3 = __expf(lrelu(l3 + adst));
    a0 += w0 * unp2(r0.x); a1 += w0 * unp2(r0.y); a2 += w0 * unp2(r0.z); a3 += w0 * unp2(r0.w);
    a0 += w1 * unp2(r1.x); a1 += w1 * unp2(r1.y); a2 += w1 * unp2(r1.z); a3 += w1 * unp2(r1.w);
    a0 += w2 * unp2(r2.x); a1 += w2 * unp2(r2.y); a2 += w2 * unp2(r2.z); a3 += w2 * unp2(r2.w);
    a0 += w3 * unp2(r3.x); a1 += w3 * unp2(r3.y); a2 += w3 * unp2(r3.z); a3 += w3 * unp2(r3.w);
    dsum += w0 + w1 + w2 + w3;
  }
  for (; e < end; e += 2) {
    int s = csr_src[e];
    float w = __expf(lrelu(as1[s * 8 + h] + adst));
    uint4 rv = *reinterpret_cast<const uint4*>(&h1b[(size_t)s * HID + sl * 8]);
    a0 += w * unp2(rv.x); a1 += w * unp2(rv.y); a2 += w * unp2(rv.z); a3 += w * unp2(rv.w);
    dsum += w;
  }
  float acc[8] = {a0.x, a0.y, a1.x, a1.y, a2.x, a2.y, a3.x, a3.y};
  #pragma unroll
  for (int j = 0; j < 8; j++) acc[j] += __shfl_xor(acc[j], 32);
  dsum += __shfl_xor(dsum, 32);
  float inv = 1.f / (dsum + 1e-16f);

  if (half == 0) {
    unsigned short ob[8];
    #pragma unroll
    for (int j = 0; j < 8; j++) {
      float o = acc[j] * inv + b1[sl * 8 + j];
      o = o > 0.f ? o : expm1f(o);
      ob[j] = f2bf(o);
    }
    uint4 pk;
    pk.x = ob[0] | ((uint)ob[1] << 16); pk.y = ob[2] | ((uint)ob[3] << 16);
    pk.z = ob[4] | ((uint)ob[5] << 16); pk.w = ob[6] | ((uint)ob[7] << 16);
    size_t addr = ((size_t)(node >> 7) * 8 + (sl >> 2)) * 4096 + (size_t)(node & 127) * 32 + (sl & 3) * 8;
    *reinterpret_cast<uint4*>(&hpb[addr]) = pk;
  }
}

// ---------------- layer-2 aggregation: unroll-4 per half ----------------
__global__ __launch_bounds__(256) void k_agg2(const float* __restrict__ h2,
                                              const int* __restrict__ indptr,
                                              const int* __restrict__ csr_src,
                                              const float* __restrict__ as2,
                                              const float* __restrict__ ad2,
                                              const float* __restrict__ b2,
                                              float* __restrict__ out) {
  int wave = threadIdx.x >> 6, lane = threadIdx.x & 63;
  int node = blockIdx.x * 4 + wave;
  if (node >= N_NODES) return;
  int beg = indptr[node], end = indptr[node + 1];
  int half = lane >> 5, sl = lane & 31;   // lane sl covers cols 2sl, 2sl+1
  float adst = ad2[node];

  f32x2 acc2 = {0.f, 0.f};
  float dsum = 0.f;
  int e = beg + half;
  for (; e + 6 < end; e += 8) {
    int s0 = csr_src[e];
    int s1 = csr_src[e + 2];
    int s2 = csr_src[e + 4];
    int s3 = csr_src[e + 6];
    float l0 = as2[s0];
    float l1 = as2[s1];
    float l2 = as2[s2];
    float l3 = as2[s3];
    f32x2 v0 = *reinterpret_cast<const f32x2*>(&h2[(size_t)s0 * OUT_C + sl * 2]);
    f32x2 v1 = *reinterpret_cast<const f32x2*>(&h2[(size_t)s1 * OUT_C + sl * 2]);
    f32x2 v2 = *reinterpret_cast<const f32x2*>(&h2[(size_t)s2 * OUT_C + sl * 2]);
    f32x2 v3 = *reinterpret_cast<const f32x2*>(&h2[(size_t)s3 * OUT_C + sl * 2]);
    float w0 = __expf(lrelu(l0 + adst));
    float w1 = __expf(lrelu(l1 + adst));
    float w2 = __expf(lrelu(l2 + adst));
    float w3 = __expf(lrelu(l3 + adst));
    acc2 += w0 * v0; acc2 += w1 * v1; acc2 += w2 * v2; acc2 += w3 * v3;
    dsum += w0 + w1 + w2 + w3;
  }
  for (; e < end; e += 2) {
    int s = csr_src[e];
    float w = __expf(lrelu(as2[s] + adst));
    f32x2 v = *reinterpret_cast<const f32x2*>(&h2[(size_t)s * OUT_C + sl * 2]);
    acc2 += w * v;
    dsum += w;
  }
  acc2.x += __shfl_xor(acc2.x, 32);
  acc2.y += __shfl_xor(acc2.y, 32);
  dsum += __shfl_xor(dsum, 32);
  float inv = 1.f / (dsum + 1e-16f);
  if (half == 0) {
    float2 o = {acc2.x * inv + b2[sl * 2], acc2.y * inv + b2[sl * 2 + 1]};
    *reinterpret_cast<float2*>(&out[(size_t)node * OUT_C + sl * 2]) = o;
  }
}

extern "C" void kernel_launch(void* const* d_in, const int* in_sizes, int n_in,
                              void* d_out, int out_size, void* d_ws, size_t ws_size,
                              hipStream_t stream) {
  const float* x     = (const float*)d_in[0];
  const int*   ei    = (const int*)d_in[1];
  const float* W1    = (const float*)d_in[2];
  const float* asrc1 = (const float*)d_in[3];
  const float* adst1 = (const float*)d_in[4];
  const float* b1    = (const float*)d_in[5];
  const float* W2    = (const float*)d_in[6];
  const float* asrc2 = (const float*)d_in[7];
  const float* adst2 = (const float*)d_in[8];
  const float* b2    = (const float*)d_in[9];
  float* out = (float*)d_out;

  char* p = (char*)d_ws;
  size_t off = 0;
  auto take = [&](size_t bytes) -> void* {
    void* r = p + off;
    off += (bytes + 255) & ~(size_t)255;
    return r;
  };
  ushort_t* h1b  = (ushort_t*)take((size_t)N_NODES * HID * 2);
  ushort_t* hpb  = (ushort_t*)take((size_t)(M_PAD / 128) * 8 * 4096 * 2);
  float*    h2   = (float*)take((size_t)N_NODES * OUT_C * 4);
  float*    as1  = (float*)take((size_t)N_NODES * HEADS * 4);
  float*    ad1  = (float*)take((size_t)N_NODES * HEADS * 4);
  float*    as2  = (float*)take((size_t)N_NODES * 4);
  float*    ad2  = (float*)take((size_t)N_NODES * 4);
  int* counts = (int*)take((size_t)N_NODES * 4);
  int* indptr = (int*)take((size_t)(N_NODES + 1) * 4);
  int* wptr   = (int*)take((size_t)(N_NODES + 1) * 4);
  int* bsum   = (int*)take((size_t)NBLK * 4);
  int* boff   = (int*)take((size_t)NBLK * 4);
  int* csr    = (int*)take((size_t)E_TOT * 4);
  ushort_t* w1t = (ushort_t*)take((size_t)IN_C * HID * 2);
  ushort_t* w2t = (ushort_t*)take((size_t)HID * OUT_C * 2);

  // CSR build (parallel scan)
  hipMemsetAsync(counts, 0, (size_t)N_NODES * 4, stream);
  k_count<<<(E_TOT + 255) / 256, 256, 0, stream>>>(ei, counts);
  k_bsum<<<NBLK, 256, 0, stream>>>(counts, bsum);
  k_bscan<<<1, 256, 0, stream>>>(bsum, boff);
  k_local<<<NBLK, 256, 0, stream>>>(counts, boff, indptr, wptr);
  k_scatter<<<(E_TOT + 255) / 256, 256, 0, stream>>>(ei, wptr, csr);

  // weight transposes
  k_conv_w1<<<(HID * IN_C + 255) / 256, 256, 0, stream>>>(W1, w1t);
  k_conv_w2<<<(OUT_C * HID + 255) / 256, 256, 0, stream>>>(W2, w2t);

  // layer 1
  k_mm1<<<M_PAD / 128, 512, 0, stream>>>(x, w1t, h1b);
  k_alpha1<<<(N_NODES * HEADS + 255) / 256, 256, 0, stream>>>(h1b, asrc1, adst1, as1, ad1);
  k_agg1<<<(N_NODES + 3) / 4, 256, 0, stream>>>(h1b, indptr, csr, as1, ad1, b1, hpb);

  // layer 2
  k_mm2<<<M_PAD / 128, 256, 0, stream>>>(hpb, w2t, h2);
  k_alpha2<<<(N_NODES + 3) / 4, 256, 0, stream>>>(h2, asrc2, adst2, as2, ad2);
  k_agg2<<<(N_NODES + 3) / 4, 256, 0, stream>>>(h2, indptr, csr, as2, ad2, b2, out);
}